// Round 1
// baseline (735.279 us; speedup 1.0000x reference)
//
#include <hip/hip_runtime.h>

#define NN 4096
#define NE 65536
#define ND 64

// ---------------- K1: per-node dot products, init accumulators ----------------
// one wave per node; lane = feature dim
__global__ void k1_node_dots(const float* __restrict__ x, const float* __restrict__ wrel,
                             const float* __restrict__ wroot, double* __restrict__ srel,
                             double* __restrict__ sroot, double* __restrict__ aggs,
                             int* __restrict__ deg) {
    int gt = blockIdx.x * blockDim.x + threadIdx.x;
    int node = gt >> 6, lane = gt & 63;
    if (node >= NN) return;
    double xv = (double)x[node * ND + lane];
    double pr = xv * (double)wrel[lane];
    double po = xv * (double)wroot[lane];
    for (int off = 32; off > 0; off >>= 1) {
        pr += __shfl_down(pr, off);
        po += __shfl_down(po, off);
    }
    if (lane == 0) {
        srel[node] = pr;
        sroot[node] = po;
        aggs[node] = 0.0;
        deg[node] = 0;
    }
}

// ---------------- K2: edge aggregation (scalar) + out-degree ----------------
__global__ void k2_edge_agg(const int* __restrict__ ei, const double* __restrict__ srel,
                            double* __restrict__ aggs, int* __restrict__ deg) {
    int e = blockIdx.x * blockDim.x + threadIdx.x;
    if (e >= NE) return;
    int s = ei[e];
    int t = ei[NE + e];
    atomicAdd(&aggs[t], srel[s]);
    atomicAdd(&deg[s], 1);
}

// ---------------- K3: scores -> stable sort keys -> bitonic sort; CSR build ----------------
__global__ void k3_sort_csr(const double* __restrict__ aggs, const double* __restrict__ sroot,
                            const float* __restrict__ bptr, const int* __restrict__ deg,
                            const int* __restrict__ ei, int* __restrict__ order,
                            int* __restrict__ rowoff, int* __restrict__ cursor,
                            int* __restrict__ csr_dst) {
    __shared__ unsigned long long keys[NN];
    __shared__ int scan[1024];
    int tid = threadIdx.x;
    double b = (double)bptr[0];

    for (int n = tid; n < NN; n += 1024) {
        double arg = aggs[n] + sroot[n] + b;
        float sc = tanhf((float)arg);           // float32 saturation => ties like reference
        unsigned u = __float_as_uint(sc);
        u = (u & 0x80000000u) ? ~u : (u | 0x80000000u);   // monotone ascending map
        unsigned hi = ~u;                                  // descending score
        keys[n] = ((unsigned long long)hi << 32) | (unsigned)n; // tie -> ascending index
    }
    __syncthreads();

    // bitonic sort 4096 u64 keys ascending
    for (int k = 2; k <= NN; k <<= 1) {
        for (int j = k >> 1; j > 0; j >>= 1) {
            for (int i = tid; i < NN; i += 1024) {
                int ixj = i ^ j;
                if (ixj > i) {
                    bool up = ((i & k) == 0);
                    unsigned long long a = keys[i], c = keys[ixj];
                    if ((a > c) == up) { keys[i] = c; keys[ixj] = a; }
                }
            }
            __syncthreads();
        }
    }
    for (int n = tid; n < NN; n += 1024) order[n] = (int)(keys[n] & 0xFFFFFFFFu);

    // exclusive prefix sum of deg -> rowoff / cursor (4 elems per thread)
    int base = tid * 4;
    int s0 = deg[base], s1 = deg[base + 1], s2 = deg[base + 2], s3 = deg[base + 3];
    int tot = s0 + s1 + s2 + s3;
    scan[tid] = tot;
    __syncthreads();
    for (int off = 1; off < 1024; off <<= 1) {
        int v = scan[tid];
        int w = (tid >= off) ? scan[tid - off] : 0;
        __syncthreads();
        scan[tid] = v + w;
        __syncthreads();
    }
    int excl = scan[tid] - tot;
    rowoff[base]     = excl;
    rowoff[base + 1] = excl + s0;
    rowoff[base + 2] = excl + s0 + s1;
    rowoff[base + 3] = excl + s0 + s1 + s2;
    cursor[base]     = excl;
    cursor[base + 1] = excl + s0;
    cursor[base + 2] = excl + s0 + s1;
    cursor[base + 3] = excl + s0 + s1 + s2;
    if (tid == 0) rowoff[NN] = NE;
    __syncthreads();

    // scatter edges into CSR (within-row order arbitrary; dest-set semantics don't care)
    for (int e = tid; e < NE; e += 1024) {
        int s = ei[e];
        int pos = atomicAdd(&cursor[s], 1);
        csr_dst[pos] = ei[NE + e];
    }
}

// ---------------- K4: sequential greedy contraction (control only), 1 wave ----------------
__global__ void __launch_bounds__(64) k4_contract(const int* __restrict__ order_g,
        const int* __restrict__ rowoff_g, const int* __restrict__ csr_dst,
        int* __restrict__ map_g, int* __restrict__ rem_g, int* __restrict__ relab_g,
        int* __restrict__ perm_a, int* __restrict__ selfa_g, int* __restrict__ cen_g,
        int* __restrict__ nkeep_g) {
    __shared__ int order[NN];
    __shared__ int rowoff[NN + 1];
    __shared__ int map[NN];
    __shared__ unsigned char rem[NN];
    __shared__ unsigned char cen[NN];
    __shared__ unsigned char selfa[NN];
    int lane = threadIdx.x;

    for (int n = lane; n < NN; n += 64) {
        order[n] = order_g[n];
        rowoff[n] = rowoff_g[n];
        map[n] = n;
        rem[n] = 1; cen[n] = 0; selfa[n] = 0;
    }
    if (lane == 0) rowoff[NN] = rowoff_g[NN];
    __syncthreads();

    int i = 0;
    while (i < NN) {
        // ballot-scan next 64 positions for the first still-remaining node
        int pos = i + lane;
        int cand = order[(pos < NN) ? pos : 0];
        bool act = (pos < NN) && (rem[cand] != 0);
        unsigned long long m = __ballot(act);
        if (m == 0ULL) { i += 64; continue; }
        i += __ffsll((unsigned long long)m) - 1;
        int u = order[i];   // wave-uniform

        int rs = rowoff[u], re = rowoff[u + 1];
        for (int bb = rs; bb < re; bb += 64) {
            int e = bb + lane;
            if (e < re) {
                int w = csr_dst[e];
                int v = map[w];
                // snapshot semantics: if w was absorbed earlier in THIS step,
                // map[w]==u but the step-start value was w itself (it was free)
                if (v == u && w != u) v = w;
                if (!cen[v]) {
                    rem[v] = 0;
                    map[v] = u;
                    if (v == u) selfa[u] = 1;   // self-loop: center absorbs itself
                }
            }
        }
        if (lane == 0) cen[u] = 1;
        ++i;
    }
    __syncthreads();

    // relabel = exclusive count of remaining; perm_a = kept nodes in index order
    int base = lane * 64;
    int cnt = 0;
    for (int t = 0; t < 64; ++t) cnt += rem[base + t];
    int inc = cnt;
    for (int off = 1; off < 64; off <<= 1) {
        int w = __shfl_up(inc, off);
        if (lane >= off) inc += w;
    }
    int excl = inc - cnt;
    int run = excl;
    for (int t = 0; t < 64; ++t) {
        int n = base + t;
        relab_g[n] = run;
        if (rem[n]) { perm_a[run] = n; ++run; }
        rem_g[n] = rem[n];
        map_g[n] = map[n];
        selfa_g[n] = selfa[n];
        cen_g[n] = cen[n];
    }
    int total = __shfl(inc, 63);
    if (lane == 0) nkeep_g[0] = total;
}

// ---------------- K5a: init center rows of xout ----------------
__global__ void k5a_init(const float* __restrict__ x, const int* __restrict__ cen_g,
                         const int* __restrict__ selfa_g, float* __restrict__ xout) {
    int idx = blockIdx.x * blockDim.x + threadIdx.x;
    if (idx >= NN * ND) return;
    int n = idx >> 6;
    if (cen_g[n]) xout[idx] = x[idx] * (selfa_g[n] ? 2.0f : 1.0f);
}

// ---------------- K5b: scatter-add absorbed nodes into their centers ----------------
__global__ void k5b_scatter(const float* __restrict__ x, const int* __restrict__ map_g,
                            float* __restrict__ xout) {
    int idx = blockIdx.x * blockDim.x + threadIdx.x;
    if (idx >= NN * ND) return;
    int n = idx >> 6, d = idx & 63;
    int m = map_g[n];
    if (m != n) atomicAdd(&xout[m * ND + d], x[idx]);
}

// ---------------- K6: assemble outputs (all as float32) ----------------
__global__ void k6_outputs(const float* __restrict__ xout, const int* __restrict__ perm_a,
                           const int* __restrict__ rem_g, const int* __restrict__ relab_g,
                           const int* __restrict__ ei, const int* __restrict__ batch,
                           const int* __restrict__ nkeep_g, float* __restrict__ out) {
    int idx = blockIdx.x * blockDim.x + threadIdx.x;
    int nk = nkeep_g[0];
    if (idx < NN * ND) {
        // x_pooled
        int r = idx >> 6, d = idx & 63;
        float v = 0.0f;
        if (r < nk) { int u = perm_a[r]; v = xout[u * ND + d]; }
        out[idx] = v;
    } else if (idx < NN * ND + 2 * NE) {
        // new_edge_index: row 0 = src, row 1 = dst
        int e = idx - NN * ND;
        int row = e >> 16;          // NE == 1<<16
        int ee = e & (NE - 1);
        int s = ei[ee], t = ei[NE + ee];
        bool valid = (rem_g[s] != 0) && (rem_g[t] != 0);
        int endp = (row == 0) ? s : t;
        out[idx] = valid ? (float)relab_g[endp] : -1.0f;
    } else if (idx < NN * ND + 2 * NE + NN) {
        // batch_pooled
        int r = idx - (NN * ND + 2 * NE);
        out[idx] = (r < nk) ? (float)batch[perm_a[r]] : -1.0f;
    } else if (idx < NN * ND + 2 * NE + 2 * NN) {
        // perm_out
        int r = idx - (NN * ND + 2 * NE + NN);
        out[idx] = (r < nk) ? (float)perm_a[r] : -1.0f;
    }
}

extern "C" void kernel_launch(void* const* d_in, const int* in_sizes, int n_in,
                              void* d_out, int out_size, void* d_ws, size_t ws_size,
                              hipStream_t stream) {
    const float* x     = (const float*)d_in[0];
    const int*   ei    = (const int*)d_in[1];
    const int*   batch = (const int*)d_in[2];
    const float* wrel  = (const float*)d_in[3];
    const float* wroot = (const float*)d_in[4];
    const float* b     = (const float*)d_in[5];

    char* ws = (char*)d_ws;
    double* srel   = (double*)(ws + 0);        // 32768 B
    double* sroot  = (double*)(ws + 32768);    // 32768 B
    double* aggs   = (double*)(ws + 65536);    // 32768 B
    float*  xout   = (float*)(ws + 98304);     // 1048576 B
    int*    csr    = (int*)(ws + 1146880);     // 262144 B
    int*    deg    = (int*)(ws + 1409024);     // 16384 B
    int*    rowoff = (int*)(ws + 1425408);     // 16388 B (padded to 16448)
    int*    cursor = (int*)(ws + 1441856);     // 16384 B
    int*    order  = (int*)(ws + 1458240);     // 16384 B
    int*    map_g  = (int*)(ws + 1474624);     // 16384 B
    int*    rem_g  = (int*)(ws + 1491008);     // 16384 B
    int*    relab  = (int*)(ws + 1507392);     // 16384 B
    int*    perma  = (int*)(ws + 1523776);     // 16384 B
    int*    selfa  = (int*)(ws + 1540160);     // 16384 B
    int*    ceng   = (int*)(ws + 1556544);     // 16384 B
    int*    nkeep  = (int*)(ws + 1572928);     // 64 B

    float* out = (float*)d_out;

    k1_node_dots<<<NN * ND / 256, 256, 0, stream>>>(x, wrel, wroot, srel, sroot, aggs, deg);
    k2_edge_agg<<<NE / 256, 256, 0, stream>>>(ei, srel, aggs, deg);
    k3_sort_csr<<<1, 1024, 0, stream>>>(aggs, sroot, b, deg, ei, order, rowoff, cursor, csr);
    k4_contract<<<1, 64, 0, stream>>>(order, rowoff, csr, map_g, rem_g, relab, perma, selfa,
                                      ceng, nkeep);
    k5a_init<<<NN * ND / 256, 256, 0, stream>>>(x, ceng, selfa, xout);
    k5b_scatter<<<NN * ND / 256, 256, 0, stream>>>(x, map_g, xout);
    int total_out = NN * ND + 2 * NE + 2 * NN;  // 401408
    k6_outputs<<<(total_out + 255) / 256, 256, 0, stream>>>(xout, perma, rem_g, relab, ei,
                                                            batch, nkeep, out);
}

// Round 2
// 591.486 us; speedup vs baseline: 1.2431x; 1.2431x over previous
//
#include <hip/hip_runtime.h>

#define NN 4096
#define NE 65536
#define ND 64

#define ABS_F 0x1000u   // node absorbed (remaining=0)
#define CEN_F 0x2000u   // node is a center

// ---------------- K1: per-node dot products, init accumulators ----------------
// one wave per node; lane = feature dim
__global__ void k1_node_dots(const float* __restrict__ x, const float* __restrict__ wrel,
                             const float* __restrict__ wroot, double* __restrict__ srel,
                             double* __restrict__ sroot, double* __restrict__ aggs,
                             int* __restrict__ deg) {
    int gt = blockIdx.x * blockDim.x + threadIdx.x;
    int node = gt >> 6, lane = gt & 63;
    if (node >= NN) return;
    double xv = (double)x[node * ND + lane];
    double pr = xv * (double)wrel[lane];
    double po = xv * (double)wroot[lane];
    for (int off = 32; off > 0; off >>= 1) {
        pr += __shfl_down(pr, off);
        po += __shfl_down(po, off);
    }
    if (lane == 0) {
        srel[node] = pr;
        sroot[node] = po;
        aggs[node] = 0.0;
        deg[node] = 0;
    }
}

// ---------------- K2: edge aggregation (scalar) + out-degree ----------------
__global__ void k2_edge_agg(const int* __restrict__ ei, const double* __restrict__ srel,
                            double* __restrict__ aggs, int* __restrict__ deg) {
    int e = blockIdx.x * blockDim.x + threadIdx.x;
    if (e >= NE) return;
    int s = ei[e];
    int t = ei[NE + e];
    atomicAdd(&aggs[t], srel[s]);
    atomicAdd(&deg[s], 1);
}

// ---------------- K3: scores -> stable sort -> packed order/row table + ushort CSR ----------
__global__ void k3_sort_csr(const double* __restrict__ aggs, const double* __restrict__ sroot,
                            const float* __restrict__ bptr, const int* __restrict__ deg,
                            const int* __restrict__ ei, unsigned* __restrict__ ordrow,
                            int* __restrict__ cursor, unsigned short* __restrict__ csr_us) {
    __shared__ unsigned long long keys[NN];
    __shared__ int scan[1024];
    __shared__ int rowstart[NN + 1];
    int tid = threadIdx.x;
    double b = (double)bptr[0];

    for (int n = tid; n < NN; n += 1024) {
        double arg = aggs[n] + sroot[n] + b;
        float sc = tanhf((float)arg);           // float32 saturation => ties like reference
        unsigned u = __float_as_uint(sc);
        u = (u & 0x80000000u) ? ~u : (u | 0x80000000u);   // monotone ascending map
        unsigned hi = ~u;                                  // descending score
        keys[n] = ((unsigned long long)hi << 32) | (unsigned)n; // tie -> ascending index
    }
    __syncthreads();

    // bitonic sort 4096 u64 keys ascending
    for (int k = 2; k <= NN; k <<= 1) {
        for (int j = k >> 1; j > 0; j >>= 1) {
            for (int i = tid; i < NN; i += 1024) {
                int ixj = i ^ j;
                if (ixj > i) {
                    bool up = ((i & k) == 0);
                    unsigned long long a = keys[i], c = keys[ixj];
                    if ((a > c) == up) { keys[i] = c; keys[ixj] = a; }
                }
            }
            __syncthreads();
        }
    }

    // exclusive prefix sum of deg -> rowstart (LDS) + cursor (global)
    int base = tid * 4;
    int s0 = deg[base], s1 = deg[base + 1], s2 = deg[base + 2], s3 = deg[base + 3];
    int tot = s0 + s1 + s2 + s3;
    scan[tid] = tot;
    __syncthreads();
    for (int off = 1; off < 1024; off <<= 1) {
        int v = scan[tid];
        int w = (tid >= off) ? scan[tid - off] : 0;
        __syncthreads();
        scan[tid] = v + w;
        __syncthreads();
    }
    int excl = scan[tid] - tot;
    rowstart[base]     = excl;
    rowstart[base + 1] = excl + s0;
    rowstart[base + 2] = excl + s0 + s1;
    rowstart[base + 3] = excl + s0 + s1 + s2;
    cursor[base]     = excl;
    cursor[base + 1] = excl + s0;
    cursor[base + 2] = excl + s0 + s1;
    cursor[base + 3] = excl + s0 + s1 + s2;
    if (tid == 0) rowstart[NN] = NE;
    __syncthreads();

    // packed per-position record: node(12b) | relstart+8192 (14b) | deg (6b)
    for (int n = tid; n < NN; n += 1024) {
        int node = (int)(keys[n] & 0xFFFu);
        int rs = rowstart[node];
        int dg = rowstart[node + 1] - rs;            // max deg ~45 << 63
        unsigned rel = (unsigned)(rs - (node << 4) + 8192);  // random walk, |dev| << 8192
        ordrow[n] = (unsigned)node | (rel << 12) | ((unsigned)dg << 26);
    }

    // scatter edges into ushort CSR (within-row order arbitrary)
    for (int e = tid; e < NE; e += 1024) {
        int s = ei[e];
        int pos = atomicAdd(&cursor[s], 1);
        csr_us[pos] = (unsigned short)ei[NE + e];
    }
}

// ---------------- K4: sequential greedy contraction, CSR fully in LDS ----------------
__global__ void __launch_bounds__(256) k4_contract(const unsigned* __restrict__ ordrow_g,
        const unsigned short* __restrict__ csr_g, int* __restrict__ map_g,
        int* __restrict__ rem_g, int* __restrict__ relab_g, int* __restrict__ perm_a,
        int* __restrict__ nkeep_g) {
    __shared__ __align__(16) unsigned short lds_csr[NE];   // 131072 B
    __shared__ __align__(16) unsigned lds_or[NN];          //  16384 B
    __shared__ volatile unsigned short st[NN];             //   8192 B: map(12b)|ABS|CEN
    __shared__ int scan2[256];                             //   1024 B  (total 156672 B)
    int tid = threadIdx.x;

    // stage CSR + order/row table into LDS with 16B vector copies (4 waves)
    const uint4* gsrc = (const uint4*)csr_g;
    uint4* ldst = (uint4*)lds_csr;
    for (int i = tid; i < NE * 2 / 16; i += 256) ldst[i] = gsrc[i];
    const uint4* gor = (const uint4*)ordrow_g;
    uint4* lor = (uint4*)lds_or;
    for (int i = tid; i < NN * 4 / 16; i += 256) lor[i] = gor[i];
    for (int n = tid; n < NN; n += 256) st[n] = (unsigned short)n;
    __syncthreads();

    if (tid < 64) {                 // single wave runs the sequential loop
        int lane = tid;
        int b = 0;                  // aligned 64-position block base
        unsigned c_cur = lds_or[lane];
        unsigned c_nxt = lds_or[64 + lane];
        int i = 0;
        while (i < NN) {
            if (i >= b + 64) {      // advance block; prefetched regs rotate
                b += 64;
                c_cur = c_nxt;
                int p = b + 64 + lane;
                c_nxt = lds_or[p < NN ? p : (NN - 1)];   // clamped; unused at last block
            }
            int node = (int)(c_cur & 0xFFFu);
            bool act = (b + lane >= i) && ((st[node] & ABS_F) == 0);
            unsigned long long m = __ballot(act);
            if (m == 0ULL) { i = b + 64; continue; }
            int first = (int)(__ffsll(m) - 1);
            i = b + first;
            unsigned cu = __shfl(c_cur, first);
            int u  = (int)(cu & 0xFFFu);
            int rs = (int)((cu >> 12) & 0x3FFFu) - 8192 + (u << 4);
            int dg = (int)(cu >> 26);
            // absorb free out-neighbors: one LDS read decides (map==self && !cen <=> !(ABS|CEN))
            if (lane < dg) {
                int w = (int)lds_csr[rs + lane];
                unsigned short sw = st[w];
                if ((sw & (ABS_F | CEN_F)) == 0)
                    st[w] = (unsigned short)((unsigned)u | ABS_F);  // dup writes: same value
            }
            if (lane == 0) st[u] = (unsigned short)(st[u] | CEN_F); // after row writes (in-order)
            ++i;
        }
    }
    __syncthreads();

    // tail: relabel prefix + perm + outputs (256 threads, 16 nodes each)
    int base = tid * 16;
    unsigned short loc[16];
    int cnt = 0;
    for (int t = 0; t < 16; ++t) { loc[t] = st[base + t]; cnt += ((loc[t] & ABS_F) == 0); }
    scan2[tid] = cnt;
    __syncthreads();
    for (int off = 1; off < 256; off <<= 1) {
        int v = scan2[tid];
        int w = (tid >= off) ? scan2[tid - off] : 0;
        __syncthreads();
        scan2[tid] = v + w;
        __syncthreads();
    }
    int run = scan2[tid] - cnt;
    for (int t = 0; t < 16; ++t) {
        int n = base + t;
        int rem = ((loc[t] & ABS_F) == 0);
        relab_g[n] = run;
        if (rem) { perm_a[run] = n; ++run; }
        rem_g[n] = rem;
        map_g[n] = (int)(loc[t] & 0xFFFu);
    }
    if (tid == 255) nkeep_g[0] = scan2[255];
}

// ---------------- K5: assemble ALL outputs (x_pooled base = original x) ----------------
__global__ void k5_outputs(const float* __restrict__ x, const int* __restrict__ perm_a,
                           const int* __restrict__ rem_g, const int* __restrict__ relab_g,
                           const int* __restrict__ ei, const int* __restrict__ batch,
                           const int* __restrict__ nkeep_g, float* __restrict__ out) {
    int idx = blockIdx.x * blockDim.x + threadIdx.x;
    int nk = nkeep_g[0];
    if (idx < NN * ND) {
        // x_pooled base: kept free nodes keep original x; centers get scatter-adds in K6
        int r = idx >> 6, d = idx & 63;
        float v = 0.0f;
        if (r < nk) { int u = perm_a[r]; v = x[u * ND + d]; }
        out[idx] = v;
    } else if (idx < NN * ND + 2 * NE) {
        int e = idx - NN * ND;
        int row = e >> 16;          // NE == 1<<16
        int ee = e & (NE - 1);
        int s = ei[ee], t = ei[NE + ee];
        bool valid = (rem_g[s] != 0) && (rem_g[t] != 0);
        int endp = (row == 0) ? s : t;
        out[idx] = valid ? (float)relab_g[endp] : -1.0f;
    } else if (idx < NN * ND + 2 * NE + NN) {
        int r = idx - (NN * ND + 2 * NE);
        out[idx] = (r < nk) ? (float)batch[perm_a[r]] : -1.0f;
    } else if (idx < NN * ND + 2 * NE + 2 * NN) {
        int r = idx - (NN * ND + 2 * NE + NN);
        out[idx] = (r < nk) ? (float)perm_a[r] : -1.0f;
    }
}

// ---------------- K6: scatter-add absorbed rows directly into out ----------------
__global__ void k6_scatter(const float* __restrict__ x, const int* __restrict__ map_g,
                           const int* __restrict__ rem_g, const int* __restrict__ relab_g,
                           float* __restrict__ out) {
    int idx = blockIdx.x * blockDim.x + threadIdx.x;
    if (idx >= NN * ND) return;
    int n = idx >> 6, d = idx & 63;
    int m = map_g[n];
    // absorbed node with a KEPT center (self-loop centers are dropped rows)
    if (m != n && rem_g[m]) atomicAdd(&out[relab_g[m] * ND + d], x[idx]);
}

extern "C" void kernel_launch(void* const* d_in, const int* in_sizes, int n_in,
                              void* d_out, int out_size, void* d_ws, size_t ws_size,
                              hipStream_t stream) {
    const float* x     = (const float*)d_in[0];
    const int*   ei    = (const int*)d_in[1];
    const int*   batch = (const int*)d_in[2];
    const float* wrel  = (const float*)d_in[3];
    const float* wroot = (const float*)d_in[4];
    const float* b     = (const float*)d_in[5];

    char* ws = (char*)d_ws;
    double*         srel   = (double*)(ws + 0);         // 32768
    double*         sroot  = (double*)(ws + 32768);     // 32768
    double*         aggs   = (double*)(ws + 65536);     // 32768
    int*            deg    = (int*)(ws + 98304);        // 16384
    int*            cursor = (int*)(ws + 114688);       // 16384
    unsigned*       ordrow = (unsigned*)(ws + 131072);  // 16384
    unsigned short* csr_us = (unsigned short*)(ws + 147456); // 131072
    int*            map_g  = (int*)(ws + 278528);       // 16384
    int*            rem_g  = (int*)(ws + 294912);       // 16384
    int*            relab  = (int*)(ws + 311296);       // 16384
    int*            perma  = (int*)(ws + 327680);       // 16384
    int*            nkeep  = (int*)(ws + 344064);       // 64

    float* out = (float*)d_out;

    k1_node_dots<<<NN * ND / 256, 256, 0, stream>>>(x, wrel, wroot, srel, sroot, aggs, deg);
    k2_edge_agg<<<NE / 256, 256, 0, stream>>>(ei, srel, aggs, deg);
    k3_sort_csr<<<1, 1024, 0, stream>>>(aggs, sroot, b, deg, ei, ordrow, cursor, csr_us);
    k4_contract<<<1, 256, 0, stream>>>(ordrow, csr_us, map_g, rem_g, relab, perma, nkeep);
    int total_out = NN * ND + 2 * NE + 2 * NN;  // 401408
    k5_outputs<<<(total_out + 255) / 256, 256, 0, stream>>>(x, perma, rem_g, relab, ei,
                                                            batch, nkeep, out);
    k6_scatter<<<NN * ND / 256, 256, 0, stream>>>(x, map_g, rem_g, relab, out);
}

// Round 3
// 451.882 us; speedup vs baseline: 1.6271x; 1.3089x over previous
//
#include <hip/hip_runtime.h>

#define NN 4096
#define NE 65536
#define ND 64

#define ABS_F 0x1000u   // node absorbed (remaining=0)
#define CEN_F 0x2000u   // node is a center

// ---------------- K1: per-node dot products, init accumulators ----------------
__global__ void k1_node_dots(const float* __restrict__ x, const float* __restrict__ wrel,
                             const float* __restrict__ wroot, double* __restrict__ srel,
                             double* __restrict__ sroot, double* __restrict__ aggs,
                             int* __restrict__ deg) {
    int gt = blockIdx.x * blockDim.x + threadIdx.x;
    int node = gt >> 6, lane = gt & 63;
    if (node >= NN) return;
    double xv = (double)x[node * ND + lane];
    double pr = xv * (double)wrel[lane];
    double po = xv * (double)wroot[lane];
    for (int off = 32; off > 0; off >>= 1) {
        pr += __shfl_down(pr, off);
        po += __shfl_down(po, off);
    }
    if (lane == 0) {
        srel[node] = pr;
        sroot[node] = po;
        aggs[node] = 0.0;
        deg[node] = 0;
    }
}

// ---------------- K2: edge aggregation (scalar) + out-degree ----------------
__global__ void k2_edge_agg(const int* __restrict__ ei, const double* __restrict__ srel,
                            double* __restrict__ aggs, int* __restrict__ deg) {
    int e = blockIdx.x * blockDim.x + threadIdx.x;
    if (e >= NE) return;
    int s = ei[e];
    int t = ei[NE + e];
    atomicAdd(&aggs[t], srel[s]);
    atomicAdd(&deg[s], 1);
}

// ---------------- K3: prefix + CSR scatter (LDS cursor) + hybrid bitonic sort ----------
__device__ __forceinline__ void cmpswap_pair(unsigned long long& a, unsigned long long& b,
                                             bool up) {
    if ((a > b) == up) { unsigned long long t = a; a = b; b = t; }
}

__global__ void __launch_bounds__(1024) k3_sort_csr(const double* __restrict__ aggs,
        const double* __restrict__ sroot, const float* __restrict__ bptr,
        const int* __restrict__ deg_g, const int* __restrict__ ei,
        unsigned* __restrict__ ordrow_g, unsigned short* __restrict__ pos_g,
        unsigned short* __restrict__ csr_g) {
    __shared__ unsigned long long keys[NN];   // 32768
    __shared__ int rowstart[NN];              // 16384
    __shared__ int cursor[NN];                // 16384
    __shared__ int wavetot[16];
    int tid = threadIdx.x;
    int lane = tid & 63, wv = tid >> 6;

    // ---- degree exclusive prefix (wave-shuffle scan, 2 barriers) ----
    int4 d4 = ((const int4*)deg_g)[tid];
    int t0 = d4.x, t1 = d4.y, t2 = d4.z, t3 = d4.w;
    int tot = t0 + t1 + t2 + t3;
    int inc = tot;
    for (int off = 1; off < 64; off <<= 1) {
        int v = __shfl_up(inc, off);
        if (lane >= off) inc += v;
    }
    if (lane == 63) wavetot[wv] = inc;
    __syncthreads();
    if (wv == 0 && lane < 16) {
        int v = wavetot[lane];
        for (int off = 1; off < 16; off <<= 1) {
            int u2 = __shfl_up(v, off);
            if (lane >= off) v += u2;
        }
        wavetot[lane] = v;
    }
    __syncthreads();
    int waveoff = (wv > 0) ? wavetot[wv - 1] : 0;
    int excl = waveoff + inc - tot;
    rowstart[4 * tid]     = excl;
    rowstart[4 * tid + 1] = excl + t0;
    rowstart[4 * tid + 2] = excl + t0 + t1;
    rowstart[4 * tid + 3] = excl + t0 + t1 + t2;
    cursor[4 * tid]     = excl;
    cursor[4 * tid + 1] = excl + t0;
    cursor[4 * tid + 2] = excl + t0 + t1;
    cursor[4 * tid + 3] = excl + t0 + t1 + t2;
    __syncthreads();

    // ---- CSR scatter: LDS cursor atomics, global u16 writes ----
    for (int e = tid; e < NE; e += 1024) {
        int s = ei[e], t = ei[NE + e];
        int p = atomicAdd(&cursor[s], 1);
        csr_g[p] = (unsigned short)t;
    }

    // ---- keys directly into registers: items i = tid + 1024*m ----
    double bv = (double)bptr[0];
    unsigned long long r[4];
    for (int m = 0; m < 4; ++m) {
        int n = tid + 1024 * m;
        double arg = aggs[n] + sroot[n] + bv;
        float sc = tanhf((float)arg);                    // f32 saturation => ref ties
        unsigned u = __float_as_uint(sc);
        u = (u & 0x80000000u) ? ~u : (u | 0x80000000u);  // monotone ascending
        r[m] = ((unsigned long long)(~u) << 32) | (unsigned)n;
    }

    // ---- k = 2..64: all j <= 32 -> pure intra-wave shfl_xor phases ----
    for (int k = 2; k <= 64; k <<= 1) {
        for (int j = k >> 1; j > 0; j >>= 1) {
            for (int m = 0; m < 4; ++m) {
                unsigned long long v = r[m];
                unsigned long long p = __shfl_xor(v, j);
                int i = tid + 1024 * m;
                bool up = ((i & k) == 0);
                bool lower = ((i & j) == 0);
                bool takemin = (up == lower);
                r[m] = takemin ? (v < p ? v : p) : (v > p ? v : p);
            }
        }
    }
    for (int m = 0; m < 4; ++m) keys[tid + 1024 * m] = r[m];
    __syncthreads();

    // ---- k = 128..4096 ----
    for (int k = 128; k <= NN; k <<= 1) {
        if (k >= 2048) {               // j >= 1024: intra-thread register pairs
            for (int m = 0; m < 4; ++m) r[m] = keys[tid + 1024 * m];
            if (k == 4096) {           // j = 2048: (0,2),(1,3), up always
                cmpswap_pair(r[0], r[2], true);
                cmpswap_pair(r[1], r[3], true);
                cmpswap_pair(r[0], r[1], true);   // j = 1024, up always
                cmpswap_pair(r[2], r[3], true);
            } else {                   // k == 2048, j = 1024
                cmpswap_pair(r[0], r[1], true);   // i&2048 == 0 -> up
                cmpswap_pair(r[2], r[3], false);  // i&2048 != 0 -> down
            }
            for (int m = 0; m < 4; ++m) keys[tid + 1024 * m] = r[m];
            __syncthreads();
        }
        for (int j = 512; j >= 64; j >>= 1) {     // LDS phases
            if (j <= (k >> 1)) {
                for (int m2 = 0; m2 < 2; ++m2) {
                    int s = tid + 1024 * m2;                      // pair site 0..2047
                    int i = ((s & ~(j - 1)) << 1) | (s & (j - 1));
                    int l = i | j;
                    bool up = ((i & k) == 0);
                    unsigned long long a = keys[i], c = keys[l];
                    if ((a > c) == up) { keys[i] = c; keys[l] = a; }
                }
                __syncthreads();
            }
        }
        // j = 32..1: intra-wave
        for (int m = 0; m < 4; ++m) r[m] = keys[tid + 1024 * m];
        for (int j = 32; j > 0; j >>= 1) {
            for (int m = 0; m < 4; ++m) {
                unsigned long long v = r[m];
                unsigned long long p = __shfl_xor(v, j);
                int i = tid + 1024 * m;
                bool up = ((i & k) == 0);
                bool lower = ((i & j) == 0);
                bool takemin = (up == lower);
                r[m] = takemin ? (v < p ? v : p) : (v > p ? v : p);
            }
        }
        for (int m = 0; m < 4; ++m) keys[tid + 1024 * m] = r[m];
        __syncthreads();
    }

    // ---- ordrow + pos emission ----
    for (int n = tid; n < NN; n += 1024) {
        int node = (int)(keys[n] & 0xFFFu);
        int rs = rowstart[node];
        int dg = deg_g[node];
        unsigned rel = (unsigned)(rs - (node << 4) + 8192);
        ordrow_g[n] = (unsigned)node | (rel << 12) | ((unsigned)dg << 26);
        pos_g[node] = (unsigned short)n;
    }
}

// ---------------- K4: sequential contraction, mask-register candidate tracking ----------
__global__ void __launch_bounds__(256) k4_contract(const unsigned* __restrict__ ordrow_g,
        const unsigned short* __restrict__ csr_g, const unsigned short* __restrict__ pos_g,
        int* __restrict__ map_g, int* __restrict__ rem_g, int* __restrict__ relab_g,
        int* __restrict__ perm_a, int* __restrict__ nkeep_g) {
    __shared__ __align__(16) char buf[163840];                 // exactly 160 KiB
    unsigned short* lds_csr = (unsigned short*)buf;            // 131072
    unsigned* lds_or = (unsigned*)(buf + 131072);              //  16384
    volatile unsigned* st = (volatile unsigned*)(buf + 147456);//  16384: pos<<16|CEN|ABS|map
    int tid = threadIdx.x;

    const uint4* gsrc = (const uint4*)csr_g;
    uint4* ldst = (uint4*)buf;
    for (int i = tid; i < 131072 / 16; i += 256) ldst[i] = gsrc[i];
    const uint4* gor = (const uint4*)ordrow_g;
    uint4* lor = (uint4*)(buf + 131072);
    for (int i = tid; i < 16384 / 16; i += 256) lor[i] = gor[i];
    for (int n = tid; n < NN; n += 256)
        st[n] = ((unsigned)pos_g[n] << 16) | (unsigned)n;
    __syncthreads();

    if (tid < 64) {
        int lane = tid;
        unsigned long long mask = 0ULL;
        int b = -64;
        unsigned c_cur = 0, c_nxt = lds_or[lane];   // block-candidate prefetch
        bool fin = false;
        while (true) {
            if (mask == 0ULL) {
                do {
                    b += 64;
                    if (b >= NN) { fin = true; break; }
                    c_cur = c_nxt;
                    int p = b + 64 + lane;
                    c_nxt = lds_or[p < NN ? p : 0];
                    unsigned sv = st[c_cur & 0xFFFu];
                    mask = __ballot((sv & (ABS_F | CEN_F)) == 0);
                } while (mask == 0ULL);
                if (fin) break;
            }
            int fb = (int)(__ffsll(mask) - 1);      // lowest free position in block
            mask &= mask - 1ULL;                    // consume it (the center)
            int ip = b + fb;
            unsigned cu = (unsigned)__builtin_amdgcn_readlane((int)c_cur, fb);
            int u  = (int)(cu & 0xFFFu);
            int rs = (int)((cu >> 12) & 0x3FFFu) - 8192 + (u << 4);
            int dg = (int)(cu >> 26);
            int w = -1, pw = -1;
            bool freew = false;
            if (lane < dg) {
                int e = rs + lane;
                w = (int)lds_csr[e];
                unsigned sw = st[w];                // ONE read: flags+map+pos
                pw = (int)(sw >> 16);
                freew = (sw & (ABS_F | CEN_F)) == 0;
                if (freew)
                    st[w] = (sw & 0xFFFF0000u) | (unsigned)u | ABS_F;
            }
            unsigned long long selfb = __ballot(freew && (w == u));
            unsigned long long killb = __ballot(freew && (pw > ip) && (pw < b + 64));
            while (killb) {                         // expected ~0.25 iterations/center
                int s = (int)(__ffsll(killb) - 1);
                killb &= killb - 1ULL;
                int p = __builtin_amdgcn_readlane(pw, s);
                mask &= ~(1ULL << (p - b));
            }
            if (lane == 0)
                st[u] = ((unsigned)ip << 16) | (unsigned)u | CEN_F
                        | (selfb ? ABS_F : 0u);
        }
    }
    __syncthreads();

    // tail: relabel prefix + perm (scan2 aliases the dead ordrow region)
    int* scan2 = (int*)(buf + 131072);
    int base = tid * 16;
    unsigned loc[16];
    int cnt = 0;
    for (int t = 0; t < 16; ++t) { loc[t] = st[base + t]; cnt += ((loc[t] & ABS_F) == 0); }
    __syncthreads();
    scan2[tid] = cnt;
    __syncthreads();
    for (int off = 1; off < 256; off <<= 1) {
        int v = scan2[tid];
        int w = (tid >= off) ? scan2[tid - off] : 0;
        __syncthreads();
        scan2[tid] = v + w;
        __syncthreads();
    }
    int run = scan2[tid] - cnt;
    for (int t = 0; t < 16; ++t) {
        int n = base + t;
        int rem = ((loc[t] & ABS_F) == 0);
        relab_g[n] = run;
        if (rem) { perm_a[run] = n; ++run; }
        rem_g[n] = rem;
        map_g[n] = (int)(loc[t] & 0xFFFu);
    }
    if (tid == 255) nkeep_g[0] = scan2[255];
}

// ---------------- K5: assemble ALL outputs (x_pooled base = original x) ----------------
__global__ void k5_outputs(const float* __restrict__ x, const int* __restrict__ perm_a,
                           const int* __restrict__ rem_g, const int* __restrict__ relab_g,
                           const int* __restrict__ ei, const int* __restrict__ batch,
                           const int* __restrict__ nkeep_g, float* __restrict__ out) {
    int idx = blockIdx.x * blockDim.x + threadIdx.x;
    int nk = nkeep_g[0];
    if (idx < NN * ND) {
        int r = idx >> 6, d = idx & 63;
        float v = 0.0f;
        if (r < nk) { int u = perm_a[r]; v = x[u * ND + d]; }
        out[idx] = v;
    } else if (idx < NN * ND + 2 * NE) {
        int e = idx - NN * ND;
        int row = e >> 16;          // NE == 1<<16
        int ee = e & (NE - 1);
        int s = ei[ee], t = ei[NE + ee];
        bool valid = (rem_g[s] != 0) && (rem_g[t] != 0);
        int endp = (row == 0) ? s : t;
        out[idx] = valid ? (float)relab_g[endp] : -1.0f;
    } else if (idx < NN * ND + 2 * NE + NN) {
        int r = idx - (NN * ND + 2 * NE);
        out[idx] = (r < nk) ? (float)batch[perm_a[r]] : -1.0f;
    } else if (idx < NN * ND + 2 * NE + 2 * NN) {
        int r = idx - (NN * ND + 2 * NE + NN);
        out[idx] = (r < nk) ? (float)perm_a[r] : -1.0f;
    }
}

// ---------------- K6: scatter-add absorbed rows directly into out ----------------
__global__ void k6_scatter(const float* __restrict__ x, const int* __restrict__ map_g,
                           const int* __restrict__ rem_g, const int* __restrict__ relab_g,
                           float* __restrict__ out) {
    int idx = blockIdx.x * blockDim.x + threadIdx.x;
    if (idx >= NN * ND) return;
    int n = idx >> 6, d = idx & 63;
    int m = map_g[n];
    if (m != n && rem_g[m]) atomicAdd(&out[relab_g[m] * ND + d], x[idx]);
}

extern "C" void kernel_launch(void* const* d_in, const int* in_sizes, int n_in,
                              void* d_out, int out_size, void* d_ws, size_t ws_size,
                              hipStream_t stream) {
    const float* x     = (const float*)d_in[0];
    const int*   ei    = (const int*)d_in[1];
    const int*   batch = (const int*)d_in[2];
    const float* wrel  = (const float*)d_in[3];
    const float* wroot = (const float*)d_in[4];
    const float* b     = (const float*)d_in[5];

    char* ws = (char*)d_ws;
    double*         srel   = (double*)(ws + 0);              // 32768
    double*         sroot  = (double*)(ws + 32768);          // 32768
    double*         aggs   = (double*)(ws + 65536);          // 32768
    int*            deg    = (int*)(ws + 98304);             // 16384
    unsigned*       ordrow = (unsigned*)(ws + 114688);       // 16384
    unsigned short* pos_g  = (unsigned short*)(ws + 131072); // 8192
    unsigned short* csr_us = (unsigned short*)(ws + 139264); // 131072
    int*            map_g  = (int*)(ws + 270336);            // 16384
    int*            rem_g  = (int*)(ws + 286720);            // 16384
    int*            relab  = (int*)(ws + 303104);            // 16384
    int*            perma  = (int*)(ws + 319488);            // 16384
    int*            nkeep  = (int*)(ws + 335872);            // 64

    float* out = (float*)d_out;

    k1_node_dots<<<NN * ND / 256, 256, 0, stream>>>(x, wrel, wroot, srel, sroot, aggs, deg);
    k2_edge_agg<<<NE / 256, 256, 0, stream>>>(ei, srel, aggs, deg);
    k3_sort_csr<<<1, 1024, 0, stream>>>(aggs, sroot, b, deg, ei, ordrow, pos_g, csr_us);
    k4_contract<<<1, 256, 0, stream>>>(ordrow, csr_us, pos_g, map_g, rem_g, relab, perma,
                                       nkeep);
    int total_out = NN * ND + 2 * NE + 2 * NN;  // 401408
    k5_outputs<<<(total_out + 255) / 256, 256, 0, stream>>>(x, perma, rem_g, relab, ei,
                                                            batch, nkeep, out);
    k6_scatter<<<NN * ND / 256, 256, 0, stream>>>(x, map_g, rem_g, relab, out);
}

// Round 4
// 294.295 us; speedup vs baseline: 2.4984x; 1.5355x over previous
//
#include <hip/hip_runtime.h>

#define NN 4096
#define NE 65536
#define ND 64

// ---------------- K1: per-node dot products, init accumulators ----------------
__global__ void k1_node_dots(const float* __restrict__ x, const float* __restrict__ wrel,
                             const float* __restrict__ wroot, double* __restrict__ srel,
                             double* __restrict__ sroot, double* __restrict__ aggs,
                             int* __restrict__ degin) {
    int gt = blockIdx.x * blockDim.x + threadIdx.x;
    int node = gt >> 6, lane = gt & 63;
    if (node >= NN) return;
    double xv = (double)x[node * ND + lane];
    double pr = xv * (double)wrel[lane];
    double po = xv * (double)wroot[lane];
    for (int off = 32; off > 0; off >>= 1) {
        pr += __shfl_down(pr, off);
        po += __shfl_down(po, off);
    }
    if (lane == 0) {
        srel[node] = pr;
        sroot[node] = po;
        aggs[node] = 0.0;
        degin[node] = 0;
    }
}

// ---------------- K2: edge aggregation (scalar) + IN-degree ----------------
__global__ void k2_edge_agg(const int* __restrict__ ei, const double* __restrict__ srel,
                            double* __restrict__ aggs, int* __restrict__ degin) {
    int e = blockIdx.x * blockDim.x + threadIdx.x;
    if (e >= NE) return;
    int s = ei[e];
    int t = ei[NE + e];
    atomicAdd(&aggs[t], srel[s]);
    atomicAdd(&degin[t], 1);
}

__device__ __forceinline__ void cmpswap_pair(unsigned long long& a, unsigned long long& b,
                                             bool up) {
    if ((a > b) == up) { unsigned long long t = a; a = b; b = t; }
}

// ---------------- K34: sort + in-CSR + parallel fixpoint contraction ----------------
// LDS: inCSR u16 [0,128K). AUX [128K,160K): keys u64 32K during sort; afterwards
// cursor i32 [0,16K) | wtC/cnt/wtF [16K,24K) | stat u16 [24K,32K).
__global__ void __launch_bounds__(1024) k34_sort_contract(
        const double* __restrict__ aggs, const double* __restrict__ sroot,
        const float* __restrict__ bptr, const int* __restrict__ degin_g,
        const int* __restrict__ ei, int* __restrict__ map_g, int* __restrict__ rem_g,
        int* __restrict__ relab_g, int* __restrict__ perm_a, int* __restrict__ nkeep_g) {
    __shared__ __align__(16) char buf[163840];
    unsigned short* incsr = (unsigned short*)buf;
    unsigned long long* keys = (unsigned long long*)(buf + 131072);
    int* cursor = (int*)(buf + 131072);
    int* wtC = (int*)(buf + 131072 + 16384);
    int* cnt = (int*)(buf + 131072 + 16384 + 64);
    int* wtF = (int*)(buf + 131072 + 16384 + 128);
    unsigned short* pstat = (unsigned short*)(buf + 131072 + 24576);
    volatile unsigned short* stat = (volatile unsigned short*)pstat;
    int tid = threadIdx.x, lane = tid & 63, wv = tid >> 6;

    // ---- Phase A: keys in registers, hybrid bitonic sort ----
    double bv = (double)bptr[0];
    unsigned long long r[4];
    for (int m = 0; m < 4; ++m) {
        int n = tid + 1024 * m;
        double arg = aggs[n] + sroot[n] + bv;
        float sc = tanhf((float)arg);                    // f32 saturation => ref ties
        unsigned u = __float_as_uint(sc);
        u = (u & 0x80000000u) ? ~u : (u | 0x80000000u);  // monotone ascending
        r[m] = ((unsigned long long)(~u) << 32) | (unsigned)n;
    }
    for (int k = 2; k <= 64; k <<= 1) {
        for (int j = k >> 1; j > 0; j >>= 1) {
            for (int m = 0; m < 4; ++m) {
                unsigned long long v = r[m];
                unsigned long long p = __shfl_xor(v, j);
                int i = tid + 1024 * m;
                bool up = ((i & k) == 0);
                bool takemin = (up == ((i & j) == 0));
                r[m] = takemin ? (v < p ? v : p) : (v > p ? v : p);
            }
        }
    }
    for (int m = 0; m < 4; ++m) keys[tid + 1024 * m] = r[m];
    __syncthreads();
    for (int k = 128; k <= NN; k <<= 1) {
        if (k >= 2048) {
            for (int m = 0; m < 4; ++m) r[m] = keys[tid + 1024 * m];
            if (k == 4096) {
                cmpswap_pair(r[0], r[2], true);
                cmpswap_pair(r[1], r[3], true);
                cmpswap_pair(r[0], r[1], true);
                cmpswap_pair(r[2], r[3], true);
            } else {
                cmpswap_pair(r[0], r[1], true);
                cmpswap_pair(r[2], r[3], false);
            }
            for (int m = 0; m < 4; ++m) keys[tid + 1024 * m] = r[m];
            __syncthreads();
        }
        for (int j = 512; j >= 64; j >>= 1) {
            if (j <= (k >> 1)) {
                for (int m2 = 0; m2 < 2; ++m2) {
                    int s = tid + 1024 * m2;
                    int i = ((s & ~(j - 1)) << 1) | (s & (j - 1));
                    int l = i | j;
                    bool up = ((i & k) == 0);
                    unsigned long long a = keys[i], c = keys[l];
                    if ((a > c) == up) { keys[i] = c; keys[l] = a; }
                }
                __syncthreads();
            }
        }
        for (int m = 0; m < 4; ++m) r[m] = keys[tid + 1024 * m];
        for (int j = 32; j > 0; j >>= 1) {
            for (int m = 0; m < 4; ++m) {
                unsigned long long v = r[m];
                unsigned long long p = __shfl_xor(v, j);
                int i = tid + 1024 * m;
                bool up = ((i & k) == 0);
                bool takemin = (up == ((i & j) == 0));
                r[m] = takemin ? (v < p ? v : p) : (v > p ? v : p);
            }
        }
        if (k < NN) {
            for (int m = 0; m < 4; ++m) keys[tid + 1024 * m] = r[m];
            __syncthreads();
        }
    }
    __syncthreads();   // all key loads done; keys region is now free

    // ---- emit stat: p(node)<<2 | state(0=unresolved) ----
    for (int m = 0; m < 4; ++m) {
        int node = (int)(r[m] & 0xFFFu);
        pstat[node] = (unsigned short)((tid + 1024 * m) << 2);
    }
    if (tid == 0) *cnt = 0;

    // ---- Phase C: in-degree exclusive prefix -> cursor (row starts) ----
    int4 d4 = ((const int4*)degin_g)[tid];
    int t0 = d4.x, t1 = d4.y, t2 = d4.z, t3 = d4.w;
    int tot = t0 + t1 + t2 + t3;
    int inc = tot;
    for (int off = 1; off < 64; off <<= 1) {
        int v = __shfl_up(inc, off);
        if (lane >= off) inc += v;
    }
    if (lane == 63) wtC[wv] = inc;
    __syncthreads();
    if (wv == 0 && lane < 16) {
        int v = wtC[lane];
        for (int off = 1; off < 16; off <<= 1) {
            int u2 = __shfl_up(v, off);
            if (lane >= off) v += u2;
        }
        wtC[lane] = v;
    }
    __syncthreads();
    int waveoff = (wv > 0) ? wtC[wv - 1] : 0;
    int excl = waveoff + inc - tot;
    cursor[4 * tid]     = excl;
    cursor[4 * tid + 1] = excl + t0;
    cursor[4 * tid + 2] = excl + t0 + t1;
    cursor[4 * tid + 3] = excl + t0 + t1 + t2;
    __syncthreads();

    // ---- Phase D: scatter in-edges (rows by dst); cursor becomes row ENDS ----
    for (int e = tid; e < NE; e += 1024) {
        int u = ei[e], v = ei[NE + e];
        int p = atomicAdd(&cursor[v], 1);
        incsr[p] = (unsigned short)u;
    }
    __syncthreads();

    // ---- Phase E: Jacobi fixpoint.  center(v) <=> no earlier in-nbr center ----
    int vbase = tid << 2;
    int pv4[4], rs4[4], re4[4];
    unsigned resolved = 0, centerm = 0, selfm = 0;
    for (int t = 0; t < 4; ++t) {
        int v = vbase + t;
        pv4[t] = (int)(stat[v] >> 2);
        rs4[t] = v ? cursor[v - 1] : 0;
        re4[t] = cursor[v];
    }
    int round = 0;
    while (true) {
        int newly = 0;
        for (int t = 0; t < 4; ++t) {
            if (resolved & (1u << t)) continue;
            int v = vbase + t, pvv = pv4[t];
            int minU = 0x7FFFFFFF, minC = 0x7FFFFFFF, argC = 0;
            bool self = false;
            for (int e = rs4[t]; e < re4[t]; ++e) {
                int u = (int)incsr[e];
                if (u == v) { self = true; continue; }
                unsigned su = stat[u];
                int pu = (int)(su >> 2);
                if (pu > pvv) continue;           // later-position: irrelevant
                unsigned s2 = su & 3u;
                if (s2 == 1u) { if (pu < minC) { minC = pu; argC = u; } }
                else if (s2 == 0u) { if (pu < minU) minU = pu; }
            }
            if (minC < minU) {                    // first absorber determined
                stat[v] = (unsigned short)((pvv << 2) | 2);
                map_g[v] = argC;
                resolved |= 1u << t; ++newly;
            } else if (minU == 0x7FFFFFFF) {      // all earlier resolved, none center
                stat[v] = (unsigned short)((pvv << 2) | 1);
                map_g[v] = v;
                centerm |= 1u << t;
                if (self) selfm |= 1u << t;
                resolved |= 1u << t; ++newly;
            }
        }
        if (newly) atomicAdd(cnt, newly);
        __syncthreads();
        int done = *(volatile int*)cnt;
        __syncthreads();
        if (done >= NN || ++round > NN) break;
    }

    // ---- Phase F: relabel prefix + perm + outputs ----
    int cnt4 = 0;
    int remb[4];
    for (int t = 0; t < 4; ++t) {
        remb[t] = ((centerm >> t) & 1) && !((selfm >> t) & 1);
        cnt4 += remb[t];
    }
    int inc2 = cnt4;
    for (int off = 1; off < 64; off <<= 1) {
        int v = __shfl_up(inc2, off);
        if (lane >= off) inc2 += v;
    }
    if (lane == 63) wtF[wv] = inc2;
    __syncthreads();
    if (wv == 0 && lane < 16) {
        int v = wtF[lane];
        for (int off = 1; off < 16; off <<= 1) {
            int u2 = __shfl_up(v, off);
            if (lane >= off) v += u2;
        }
        wtF[lane] = v;
    }
    __syncthreads();
    int woff2 = (wv > 0) ? wtF[wv - 1] : 0;
    int run = woff2 + inc2 - cnt4;
    for (int t = 0; t < 4; ++t) {
        int v = vbase + t;
        relab_g[v] = run;
        if (remb[t]) { perm_a[run] = v; ++run; }
        rem_g[v] = remb[t];
    }
    if (tid == 1023) nkeep_g[0] = run;
}

// ---------------- K5: assemble ALL outputs (x_pooled base = original x) ----------------
__global__ void k5_outputs(const float* __restrict__ x, const int* __restrict__ perm_a,
                           const int* __restrict__ rem_g, const int* __restrict__ relab_g,
                           const int* __restrict__ ei, const int* __restrict__ batch,
                           const int* __restrict__ nkeep_g, float* __restrict__ out) {
    int idx = blockIdx.x * blockDim.x + threadIdx.x;
    int nk = nkeep_g[0];
    if (idx < NN * ND) {
        int r = idx >> 6, d = idx & 63;
        float v = 0.0f;
        if (r < nk) { int u = perm_a[r]; v = x[u * ND + d]; }
        out[idx] = v;
    } else if (idx < NN * ND + 2 * NE) {
        int e = idx - NN * ND;
        int row = e >> 16;          // NE == 1<<16
        int ee = e & (NE - 1);
        int s = ei[ee], t = ei[NE + ee];
        bool valid = (rem_g[s] != 0) && (rem_g[t] != 0);
        int endp = (row == 0) ? s : t;
        out[idx] = valid ? (float)relab_g[endp] : -1.0f;
    } else if (idx < NN * ND + 2 * NE + NN) {
        int r = idx - (NN * ND + 2 * NE);
        out[idx] = (r < nk) ? (float)batch[perm_a[r]] : -1.0f;
    } else if (idx < NN * ND + 2 * NE + 2 * NN) {
        int r = idx - (NN * ND + 2 * NE + NN);
        out[idx] = (r < nk) ? (float)perm_a[r] : -1.0f;
    }
}

// ---------------- K6: scatter-add absorbed rows directly into out ----------------
__global__ void k6_scatter(const float* __restrict__ x, const int* __restrict__ map_g,
                           const int* __restrict__ rem_g, const int* __restrict__ relab_g,
                           float* __restrict__ out) {
    int idx = blockIdx.x * blockDim.x + threadIdx.x;
    if (idx >= NN * ND) return;
    int n = idx >> 6, d = idx & 63;
    int m = map_g[n];
    if (m != n && rem_g[m]) atomicAdd(&out[relab_g[m] * ND + d], x[idx]);
}

extern "C" void kernel_launch(void* const* d_in, const int* in_sizes, int n_in,
                              void* d_out, int out_size, void* d_ws, size_t ws_size,
                              hipStream_t stream) {
    const float* x     = (const float*)d_in[0];
    const int*   ei    = (const int*)d_in[1];
    const int*   batch = (const int*)d_in[2];
    const float* wrel  = (const float*)d_in[3];
    const float* wroot = (const float*)d_in[4];
    const float* b     = (const float*)d_in[5];

    char* ws = (char*)d_ws;
    double* srel  = (double*)(ws + 0);        // 32768
    double* sroot = (double*)(ws + 32768);    // 32768
    double* aggs  = (double*)(ws + 65536);    // 32768
    int*    degin = (int*)(ws + 98304);       // 16384
    int*    map_g = (int*)(ws + 114688);      // 16384
    int*    rem_g = (int*)(ws + 131072);      // 16384
    int*    relab = (int*)(ws + 147456);      // 16384
    int*    perma = (int*)(ws + 163840);      // 16384
    int*    nkeep = (int*)(ws + 180224);      // 64

    float* out = (float*)d_out;

    k1_node_dots<<<NN * ND / 256, 256, 0, stream>>>(x, wrel, wroot, srel, sroot, aggs, degin);
    k2_edge_agg<<<NE / 256, 256, 0, stream>>>(ei, srel, aggs, degin);
    k34_sort_contract<<<1, 1024, 0, stream>>>(aggs, sroot, b, degin, ei, map_g, rem_g,
                                              relab, perma, nkeep);
    int total_out = NN * ND + 2 * NE + 2 * NN;  // 401408
    k5_outputs<<<(total_out + 255) / 256, 256, 0, stream>>>(x, perma, rem_g, relab, ei,
                                                            batch, nkeep, out);
    k6_scatter<<<NN * ND / 256, 256, 0, stream>>>(x, map_g, rem_g, relab, out);
}

// Round 5
// 208.045 us; speedup vs baseline: 3.5342x; 1.4146x over previous
//
#include <hip/hip_runtime.h>

#define NN 4096
#define NE 65536
#define ND 64

// ---------------- K1: per-node dot products (srel, sroot only) ----------------
__global__ void k1_node_dots(const float* __restrict__ x, const float* __restrict__ wrel,
                             const float* __restrict__ wroot, double* __restrict__ srel,
                             double* __restrict__ sroot) {
    int gt = blockIdx.x * blockDim.x + threadIdx.x;
    int node = gt >> 6, lane = gt & 63;
    if (node >= NN) return;
    double xv = (double)x[node * ND + lane];
    double pr = xv * (double)wrel[lane];
    double po = xv * (double)wroot[lane];
    for (int off = 32; off > 0; off >>= 1) {
        pr += __shfl_down(pr, off);
        po += __shfl_down(po, off);
    }
    if (lane == 0) {
        srel[node] = pr;
        sroot[node] = po;
    }
}

__device__ __forceinline__ void cmpswap_pair(unsigned long long& a, unsigned long long& b,
                                             bool up) {
    if ((a > b) == up) { unsigned long long t = a; a = b; b = t; }
}

// ---------------- K34: count + CSR + aggs-gather + sort + compaction fixpoint ----------
// LDS: incsr u16 [0,128K).  aux 32K = [128K,160K):
//   phases 1-3: cursor i32 [0,16K), wt ints @+20544
//   phase  4  : aggs f64 [0,32K)
//   phase  5  : keys u64 [0,32K)  (sort)
//   phase  6+ : stat u8 [0,4K) | pos2node u16 [4K,12K) | posof u16 [12K,20K)
//               | cnt @+20480 | wt @+20544
__global__ void __launch_bounds__(1024) k34_sort_contract(
        const double* __restrict__ srel, const double* __restrict__ sroot,
        const float* __restrict__ bptr, const int* __restrict__ ei,
        int* __restrict__ map_g, int* __restrict__ rem_g, int* __restrict__ relab_g,
        int* __restrict__ perm_a, int* __restrict__ nkeep_g) {
    __shared__ __align__(16) char buf[163840];
    unsigned short* incsr = (unsigned short*)buf;
    char* aux = buf + 131072;
    int* cursor = (int*)aux;
    double* aggs_d = (double*)aux;
    unsigned long long* keys = (unsigned long long*)aux;
    volatile unsigned char* stat = (volatile unsigned char*)aux;
    unsigned short* pos2node = (unsigned short*)(aux + 4096);
    unsigned short* posof = (unsigned short*)(aux + 12288);
    int* cnt = (int*)(aux + 20480);
    int* wt = (int*)(aux + 20544);
    int tid = threadIdx.x, lane = tid & 63, wv = tid >> 6;

    // ---- Phase 1: in-degree count (LDS atomics) ----
    for (int n = tid; n < NN; n += 1024) cursor[n] = 0;
    __syncthreads();
    const int4* eid4 = (const int4*)(ei + NE);
    for (int i = tid; i < NE / 4; i += 1024) {
        int4 q = eid4[i];
        atomicAdd(&cursor[q.x], 1);
        atomicAdd(&cursor[q.y], 1);
        atomicAdd(&cursor[q.z], 1);
        atomicAdd(&cursor[q.w], 1);
    }
    __syncthreads();

    // ---- Phase 2: exclusive prefix (wave scan); stash row starts in regs ----
    int t0 = cursor[4 * tid], t1 = cursor[4 * tid + 1];
    int t2 = cursor[4 * tid + 2], t3 = cursor[4 * tid + 3];
    int tot = t0 + t1 + t2 + t3;
    int inc = tot;
    for (int off = 1; off < 64; off <<= 1) {
        int v = __shfl_up(inc, off);
        if (lane >= off) inc += v;
    }
    if (lane == 63) wt[wv] = inc;
    __syncthreads();
    if (wv == 0 && lane < 16) {
        int v = wt[lane];
        for (int off = 1; off < 16; off <<= 1) {
            int u2 = __shfl_up(v, off);
            if (lane >= off) v += u2;
        }
        wt[lane] = v;
    }
    __syncthreads();
    int waveoff = (wv > 0) ? wt[wv - 1] : 0;
    int excl = waveoff + inc - tot;
    int rs4[4], re4[4];
    rs4[0] = excl; rs4[1] = excl + t0; rs4[2] = excl + t0 + t1; rs4[3] = excl + t0 + t1 + t2;
    cursor[4 * tid]     = rs4[0];
    cursor[4 * tid + 1] = rs4[1];
    cursor[4 * tid + 2] = rs4[2];
    cursor[4 * tid + 3] = rs4[3];
    __syncthreads();

    // ---- Phase 3: scatter in-edges (row = dst, entry = src node id) ----
    const int4* eis4 = (const int4*)ei;
    for (int i = tid; i < NE / 4; i += 1024) {
        int4 s = eis4[i];
        int4 d = eid4[i];
        incsr[atomicAdd(&cursor[d.x], 1)] = (unsigned short)s.x;
        incsr[atomicAdd(&cursor[d.y], 1)] = (unsigned short)s.y;
        incsr[atomicAdd(&cursor[d.z], 1)] = (unsigned short)s.z;
        incsr[atomicAdd(&cursor[d.w], 1)] = (unsigned short)s.w;
    }
    __syncthreads();
    for (int t = 0; t < 4; ++t) re4[t] = cursor[4 * tid + t];   // row ends
    __syncthreads();   // cursor region now free

    // ---- Phase 4: aggs by row-gather of srel (deterministic order) ----
    for (int t = 0; t < 4; ++t) {
        int v = 4 * tid + t;
        double s = 0.0;
        for (int e = rs4[t]; e < re4[t]; ++e) s += srel[(int)incsr[e]];
        aggs_d[v] = s;
    }
    __syncthreads();

    // ---- Phase 5: keys + hybrid bitonic sort ----
    double bv = (double)bptr[0];
    unsigned long long r[4];
    for (int m = 0; m < 4; ++m) {
        int n = tid + 1024 * m;
        double arg = aggs_d[n] + sroot[n] + bv;
        float sc = tanhf((float)arg);                    // f32 saturation => ref ties
        unsigned u = __float_as_uint(sc);
        u = (u & 0x80000000u) ? ~u : (u | 0x80000000u);  // monotone ascending
        r[m] = ((unsigned long long)(~u) << 32) | (unsigned)n;
    }
    for (int k = 2; k <= 64; k <<= 1) {
        for (int j = k >> 1; j > 0; j >>= 1) {
            for (int m = 0; m < 4; ++m) {
                unsigned long long v = r[m];
                unsigned long long p = __shfl_xor(v, j);
                int i = tid + 1024 * m;
                bool up = ((i & k) == 0);
                bool takemin = (up == ((i & j) == 0));
                r[m] = takemin ? (v < p ? v : p) : (v > p ? v : p);
            }
        }
    }
    __syncthreads();   // aggs_d reads done everywhere before keys writes
    for (int m = 0; m < 4; ++m) keys[tid + 1024 * m] = r[m];
    __syncthreads();
    for (int k = 128; k <= NN; k <<= 1) {
        if (k >= 2048) {
            for (int m = 0; m < 4; ++m) r[m] = keys[tid + 1024 * m];
            if (k == 4096) {
                cmpswap_pair(r[0], r[2], true);
                cmpswap_pair(r[1], r[3], true);
                cmpswap_pair(r[0], r[1], true);
                cmpswap_pair(r[2], r[3], true);
            } else {
                cmpswap_pair(r[0], r[1], true);
                cmpswap_pair(r[2], r[3], false);
            }
            for (int m = 0; m < 4; ++m) keys[tid + 1024 * m] = r[m];
            __syncthreads();
        }
        for (int j = 512; j >= 64; j >>= 1) {
            if (j <= (k >> 1)) {
                for (int m2 = 0; m2 < 2; ++m2) {
                    int s = tid + 1024 * m2;
                    int i = ((s & ~(j - 1)) << 1) | (s & (j - 1));
                    int l = i | j;
                    bool up = ((i & k) == 0);
                    unsigned long long a = keys[i], c = keys[l];
                    if ((a > c) == up) { keys[i] = c; keys[l] = a; }
                }
                __syncthreads();
            }
        }
        for (int m = 0; m < 4; ++m) r[m] = keys[tid + 1024 * m];
        for (int j = 32; j > 0; j >>= 1) {
            for (int m = 0; m < 4; ++m) {
                unsigned long long v = r[m];
                unsigned long long p = __shfl_xor(v, j);
                int i = tid + 1024 * m;
                bool up = ((i & k) == 0);
                bool takemin = (up == ((i & j) == 0));
                r[m] = takemin ? (v < p ? v : p) : (v > p ? v : p);
            }
        }
        if (k < NN) {
            for (int m = 0; m < 4; ++m) keys[tid + 1024 * m] = r[m];
            __syncthreads();
        }
    }
    // last LDS read of keys was before the final barrier inside the j-loop;
    // emission below writes the same aux region from registers only.

    // ---- Phase 6: emit position tables; zero stat ----
    for (int m = 0; m < 4; ++m) {
        int i = tid + 1024 * m;
        int node = (int)(r[m] & 0xFFFu);
        pos2node[i] = (unsigned short)node;
        posof[node] = (unsigned short)i;
        stat[i] = 0;
    }
    if (tid == 0) *cnt = 0;
    __syncthreads();

    // ---- Phase 7, round 0: translate rows to positions, drop later/self ----
    int pv4[4], minC4[4];
    unsigned resolved = 0, centerm = 0, selfm = 0;
    int newly = 0;
    for (int t = 0; t < 4; ++t) {
        int v = 4 * tid + t;
        int pv = (int)posof[v];
        pv4[t] = pv;
        minC4[t] = 0x7FFFFFFF;
        int w = rs4[t];
        for (int e = rs4[t]; e < re4[t]; ++e) {
            int u = (int)incsr[e];
            if (u == v) { selfm |= 1u << t; continue; }
            int pu = (int)posof[u];
            if (pu < pv) incsr[w++] = (unsigned short)pu;
        }
        re4[t] = w;
        if (w == rs4[t]) {                       // no earlier in-nbrs: center
            stat[pv] = 1;
            map_g[v] = v;
            centerm |= 1u << t; resolved |= 1u << t; ++newly;
        }
    }
    if (newly) atomicAdd(cnt, newly);
    __syncthreads();
    int done = *(volatile int*)cnt;
    __syncthreads();

    // ---- Phase 7: compaction fixpoint (monotone: entries visited while unresolved) --
    int round = 0;
    while (done < NN && round < NN) {
        newly = 0;
        for (int t = 0; t < 4; ++t) {
            if (resolved & (1u << t)) continue;
            int v = 4 * tid + t, pv = pv4[t];
            int lo = rs4[t], hi = re4[t];
            int minU = 0x7FFFFFFF, mC = minC4[t];
            int w = lo;
            for (int e = lo; e < hi; ++e) {
                int pu = (int)incsr[e];
                int st = stat[pu];
                if (st == 0) { incsr[w++] = (unsigned short)pu; if (pu < minU) minU = pu; }
                else if (st == 1) { if (pu < mC) mC = pu; }
                // st==2: absorbed, drop
            }
            re4[t] = w; minC4[t] = mC;
            if (mC < minU) {                     // first absorber known
                stat[pv] = 2;
                map_g[v] = (int)pos2node[mC];
                resolved |= 1u << t; ++newly;
            } else if (w == lo) {                // all earlier resolved non-center
                stat[pv] = 1;
                map_g[v] = v;
                centerm |= 1u << t; resolved |= 1u << t; ++newly;
            }
        }
        if (newly) atomicAdd(cnt, newly);
        __syncthreads();
        done = *(volatile int*)cnt;
        __syncthreads();
        ++round;
    }

    // ---- Phase F: relabel prefix + perm + globals ----
    int remb[4], cnt4 = 0;
    for (int t = 0; t < 4; ++t) {
        remb[t] = ((centerm >> t) & 1) && !((selfm >> t) & 1);
        cnt4 += remb[t];
    }
    int inc2 = cnt4;
    for (int off = 1; off < 64; off <<= 1) {
        int v = __shfl_up(inc2, off);
        if (lane >= off) inc2 += v;
    }
    if (lane == 63) wt[wv] = inc2;
    __syncthreads();
    if (wv == 0 && lane < 16) {
        int v = wt[lane];
        for (int off = 1; off < 16; off <<= 1) {
            int u2 = __shfl_up(v, off);
            if (lane >= off) v += u2;
        }
        wt[lane] = v;
    }
    __syncthreads();
    int woff2 = (wv > 0) ? wt[wv - 1] : 0;
    int run = woff2 + inc2 - cnt4;
    for (int t = 0; t < 4; ++t) {
        int v = 4 * tid + t;
        relab_g[v] = run;
        if (remb[t]) { perm_a[run] = v; ++run; }
        rem_g[v] = remb[t];
    }
    if (tid == 1023) nkeep_g[0] = run;
}

// ---------------- K56: all outputs; x region is pure atomic-add over memset-0 --------
__global__ void k56_outputs(const float* __restrict__ x, const int* __restrict__ map_g,
                            const int* __restrict__ rem_g, const int* __restrict__ relab_g,
                            const int* __restrict__ perm_a, const int* __restrict__ ei,
                            const int* __restrict__ batch, const int* __restrict__ nkeep_g,
                            float* __restrict__ out) {
    int idx = blockIdx.x * blockDim.x + threadIdx.x;
    if (idx < NN * ND) {
        int n = idx >> 6, d = idx & 63;
        int m = map_g[n];                 // m==n for centers & kept free nodes
        if (rem_g[m]) atomicAdd(&out[relab_g[m] * ND + d], x[idx]);
    } else if (idx < NN * ND + 2 * NE) {
        int e = idx - NN * ND;
        int row = e >> 16;                // NE == 1<<16
        int ee = e & (NE - 1);
        int s = ei[ee], t = ei[NE + ee];
        bool valid = (rem_g[s] != 0) && (rem_g[t] != 0);
        int endp = (row == 0) ? s : t;
        out[idx] = valid ? (float)relab_g[endp] : -1.0f;
    } else if (idx < NN * ND + 2 * NE + NN) {
        int r = idx - (NN * ND + 2 * NE);
        int nk = nkeep_g[0];
        out[idx] = (r < nk) ? (float)batch[perm_a[r]] : -1.0f;
    } else if (idx < NN * ND + 2 * NE + 2 * NN) {
        int r = idx - (NN * ND + 2 * NE + NN);
        int nk = nkeep_g[0];
        out[idx] = (r < nk) ? (float)perm_a[r] : -1.0f;
    }
}

extern "C" void kernel_launch(void* const* d_in, const int* in_sizes, int n_in,
                              void* d_out, int out_size, void* d_ws, size_t ws_size,
                              hipStream_t stream) {
    const float* x     = (const float*)d_in[0];
    const int*   ei    = (const int*)d_in[1];
    const int*   batch = (const int*)d_in[2];
    const float* wrel  = (const float*)d_in[3];
    const float* wroot = (const float*)d_in[4];
    const float* b     = (const float*)d_in[5];

    char* ws = (char*)d_ws;
    double* srel  = (double*)(ws + 0);        // 32768
    double* sroot = (double*)(ws + 32768);    // 32768
    int*    map_g = (int*)(ws + 65536);       // 16384
    int*    rem_g = (int*)(ws + 81920);       // 16384
    int*    relab = (int*)(ws + 98304);       // 16384
    int*    perma = (int*)(ws + 114688);      // 16384
    int*    nkeep = (int*)(ws + 131072);      // 64

    float* out = (float*)d_out;

    hipMemsetAsync(out, 0, NN * ND * sizeof(float), stream);   // x_pooled base = 0
    k1_node_dots<<<NN * ND / 256, 256, 0, stream>>>(x, wrel, wroot, srel, sroot);
    k34_sort_contract<<<1, 1024, 0, stream>>>(srel, sroot, b, ei, map_g, rem_g, relab,
                                              perma, nkeep);
    int total_out = NN * ND + 2 * NE + 2 * NN;  // 401408
    k56_outputs<<<(total_out + 255) / 256, 256, 0, stream>>>(x, map_g, rem_g, relab,
                                                             perma, ei, batch, nkeep, out);
}

// Round 6
// 196.477 us; speedup vs baseline: 3.7423x; 1.0589x over previous
//
#include <hip/hip_runtime.h>

#define NN 4096
#define NE 65536
#define ND 64

// ---------------- K1: per-node dot products (srel, sroot only) ----------------
__global__ void k1_node_dots(const float* __restrict__ x, const float* __restrict__ wrel,
                             const float* __restrict__ wroot, double* __restrict__ srel,
                             double* __restrict__ sroot) {
    int gt = blockIdx.x * blockDim.x + threadIdx.x;
    int node = gt >> 6, lane = gt & 63;
    if (node >= NN) return;
    double xv = (double)x[node * ND + lane];
    double pr = xv * (double)wrel[lane];
    double po = xv * (double)wroot[lane];
    for (int off = 32; off > 0; off >>= 1) {
        pr += __shfl_down(pr, off);
        po += __shfl_down(po, off);
    }
    if (lane == 0) {
        srel[node] = pr;
        sroot[node] = po;
    }
}

__device__ __forceinline__ void cmpswap_pair(unsigned long long& a, unsigned long long& b,
                                             bool up) {
    if ((a > b) == up) { unsigned long long t = a; a = b; b = t; }
}

// ---------------- K34: count + CSR + fused agg/keys + sort + barrier-free fixpoint ----
// LDS: incsr u16 [0,128K).  aux 32K = [128K,160K):
//   phases 1-3: cursor i32 [0,16K) | wt @+20544
//   phase  5  : keys u64 [0,32K)  (sort)
//   phase  6+ : stat u8 [0,4K) | pos2node u16 [4K,12K) | posof u16 [12K,20K) | wt @+20544
__global__ void __launch_bounds__(1024) k34_sort_contract(
        const double* __restrict__ srel, const double* __restrict__ sroot,
        const float* __restrict__ bptr, const int* __restrict__ ei,
        int* __restrict__ map_g, int* __restrict__ rem_g, int* __restrict__ relab_g,
        int* __restrict__ perm_a, int* __restrict__ nkeep_g) {
    __shared__ __align__(16) char buf[163840];
    unsigned short* incsr = (unsigned short*)buf;
    char* aux = buf + 131072;
    int* cursor = (int*)aux;
    unsigned long long* keys = (unsigned long long*)aux;
    volatile unsigned char* stat = (volatile unsigned char*)aux;
    unsigned short* pos2node = (unsigned short*)(aux + 4096);
    unsigned short* posof = (unsigned short*)(aux + 12288);
    int* wt = (int*)(aux + 20544);
    int tid = threadIdx.x, lane = tid & 63, wv = tid >> 6;

    // ---- Phase 1: in-degree count (LDS atomics) ----
    for (int n = tid; n < NN; n += 1024) cursor[n] = 0;
    __syncthreads();
    const int4* eid4 = (const int4*)(ei + NE);
    for (int i = tid; i < NE / 4; i += 1024) {
        int4 q = eid4[i];
        atomicAdd(&cursor[q.x], 1);
        atomicAdd(&cursor[q.y], 1);
        atomicAdd(&cursor[q.z], 1);
        atomicAdd(&cursor[q.w], 1);
    }
    __syncthreads();

    // ---- Phase 2: exclusive prefix (wave scan); row starts in regs ----
    int t0 = cursor[4 * tid], t1 = cursor[4 * tid + 1];
    int t2 = cursor[4 * tid + 2], t3 = cursor[4 * tid + 3];
    int tot = t0 + t1 + t2 + t3;
    int inc = tot;
    for (int off = 1; off < 64; off <<= 1) {
        int v = __shfl_up(inc, off);
        if (lane >= off) inc += v;
    }
    if (lane == 63) wt[wv] = inc;
    __syncthreads();
    if (wv == 0 && lane < 16) {
        int v = wt[lane];
        for (int off = 1; off < 16; off <<= 1) {
            int u2 = __shfl_up(v, off);
            if (lane >= off) v += u2;
        }
        wt[lane] = v;
    }
    __syncthreads();
    int waveoff = (wv > 0) ? wt[wv - 1] : 0;
    int excl = waveoff + inc - tot;
    int rs4[4], re4[4];
    rs4[0] = excl; rs4[1] = excl + t0; rs4[2] = excl + t0 + t1; rs4[3] = excl + t0 + t1 + t2;
    cursor[4 * tid]     = rs4[0];
    cursor[4 * tid + 1] = rs4[1];
    cursor[4 * tid + 2] = rs4[2];
    cursor[4 * tid + 3] = rs4[3];
    __syncthreads();

    // ---- Phase 3: scatter in-edges (row = dst, entry = src node id) ----
    const int4* eis4 = (const int4*)ei;
    for (int i = tid; i < NE / 4; i += 1024) {
        int4 s = eis4[i];
        int4 d = eid4[i];
        incsr[atomicAdd(&cursor[d.x], 1)] = (unsigned short)s.x;
        incsr[atomicAdd(&cursor[d.y], 1)] = (unsigned short)s.y;
        incsr[atomicAdd(&cursor[d.z], 1)] = (unsigned short)s.z;
        incsr[atomicAdd(&cursor[d.w], 1)] = (unsigned short)s.w;
    }
    __syncthreads();
    for (int t = 0; t < 4; ++t) re4[t] = cursor[4 * tid + t];   // row ends
    __syncthreads();   // cursor region now free (keys will alias it)

    // ---- Phase 5: fused agg-gather + keys (regs) + hybrid bitonic sort ----
    // ownership: item i = tid + 1024*t initially holds node v = 4*tid + t (any
    // initial placement is fine for a full bitonic sort; key low bits = node id)
    double bv = (double)bptr[0];
    unsigned long long r[4];
    for (int t = 0; t < 4; ++t) {
        int v = 4 * tid + t;
        double s = 0.0;
        for (int e = rs4[t]; e < re4[t]; ++e) s += srel[(int)incsr[e]];
        double arg = s + sroot[v] + bv;
        float sc = tanhf((float)arg);                    // f32 saturation => ref ties
        unsigned u = __float_as_uint(sc);
        u = (u & 0x80000000u) ? ~u : (u | 0x80000000u);  // monotone ascending
        r[t] = ((unsigned long long)(~u) << 32) | (unsigned)v;
    }
    for (int k = 2; k <= 64; k <<= 1) {
        for (int j = k >> 1; j > 0; j >>= 1) {
            for (int m = 0; m < 4; ++m) {
                unsigned long long v = r[m];
                unsigned long long p = __shfl_xor(v, j);
                int i = tid + 1024 * m;
                bool up = ((i & k) == 0);
                bool takemin = (up == ((i & j) == 0));
                r[m] = takemin ? (v < p ? v : p) : (v > p ? v : p);
            }
        }
    }
    for (int m = 0; m < 4; ++m) keys[tid + 1024 * m] = r[m];
    __syncthreads();
    for (int k = 128; k <= NN; k <<= 1) {
        if (k >= 2048) {
            for (int m = 0; m < 4; ++m) r[m] = keys[tid + 1024 * m];
            if (k == 4096) {
                cmpswap_pair(r[0], r[2], true);
                cmpswap_pair(r[1], r[3], true);
                cmpswap_pair(r[0], r[1], true);
                cmpswap_pair(r[2], r[3], true);
            } else {
                cmpswap_pair(r[0], r[1], true);
                cmpswap_pair(r[2], r[3], false);
            }
            for (int m = 0; m < 4; ++m) keys[tid + 1024 * m] = r[m];
            __syncthreads();
        }
        for (int j = 512; j >= 64; j >>= 1) {
            if (j <= (k >> 1)) {
                for (int m2 = 0; m2 < 2; ++m2) {
                    int s = tid + 1024 * m2;
                    int i = ((s & ~(j - 1)) << 1) | (s & (j - 1));
                    int l = i | j;
                    bool up = ((i & k) == 0);
                    unsigned long long a = keys[i], c = keys[l];
                    if ((a > c) == up) { keys[i] = c; keys[l] = a; }
                }
                __syncthreads();
            }
        }
        for (int m = 0; m < 4; ++m) r[m] = keys[tid + 1024 * m];
        for (int j = 32; j > 0; j >>= 1) {
            for (int m = 0; m < 4; ++m) {
                unsigned long long v = r[m];
                unsigned long long p = __shfl_xor(v, j);
                int i = tid + 1024 * m;
                bool up = ((i & k) == 0);
                bool takemin = (up == ((i & j) == 0));
                r[m] = takemin ? (v < p ? v : p) : (v > p ? v : p);
            }
        }
        if (k < NN) {
            for (int m = 0; m < 4; ++m) keys[tid + 1024 * m] = r[m];
            __syncthreads();
        }
    }
    __syncthreads();   // all keys READS done before stat/pos tables overwrite the region

    // ---- Phase 6: emit position tables; zero stat ----
    for (int m = 0; m < 4; ++m) {
        int i = tid + 1024 * m;
        int node = (int)(r[m] & 0xFFFu);
        pos2node[i] = (unsigned short)node;
        posof[node] = (unsigned short)i;
        stat[i] = 0;
    }
    __syncthreads();

    // ---- Phase 7a: translate rows to positions, drop later/self; trivial centers ----
    int pv4[4], minC4[4];
    unsigned resolved = 0, centerm = 0, selfm = 0;
    for (int t = 0; t < 4; ++t) {
        int v = 4 * tid + t;
        int pv = (int)posof[v];
        pv4[t] = pv;
        minC4[t] = 0x7FFFFFFF;
        int w = rs4[t];
        for (int e = rs4[t]; e < re4[t]; ++e) {
            int u = (int)incsr[e];
            if (u == v) { selfm |= 1u << t; continue; }
            int pu = (int)posof[u];
            if (pu < pv) incsr[w++] = (unsigned short)pu;
        }
        re4[t] = w;
        if (w == rs4[t]) {                       // no earlier in-nbrs: center
            stat[pv] = 1;
            map_g[v] = v;
            centerm |= 1u << t; resolved |= 1u << t;
        }
    }

    // ---- Phase 7b: BARRIER-FREE monotone dataflow fixpoint ----
    // stat transitions 0 -> {1,2} exactly once; spin until my 4 nodes resolve.
    int guard = 0;
    while (resolved != 0xFu && guard < 2000000) {
        ++guard;
        for (int t = 0; t < 4; ++t) {
            if (resolved & (1u << t)) continue;
            int v = 4 * tid + t, pv = pv4[t];
            int lo = rs4[t], hi = re4[t];
            int minU = 0x7FFFFFFF, mC = minC4[t];
            int w = lo;
            for (int e = lo; e < hi; ++e) {
                int pu = (int)incsr[e];
                int st = stat[pu];
                if (st == 0) { incsr[w++] = (unsigned short)pu; if (pu < minU) minU = pu; }
                else if (st == 1) { if (pu < mC) mC = pu; }
                // st==2: absorbed, drop
            }
            re4[t] = w; minC4[t] = mC;
            if (mC < minU) {                     // first absorber known
                map_g[v] = (int)pos2node[mC];
                stat[pv] = 2;
                resolved |= 1u << t;
            } else if (w == lo) {                // all earlier resolved non-center
                map_g[v] = v;
                stat[pv] = 1;
                centerm |= 1u << t; resolved |= 1u << t;
            }
        }
    }
    __syncthreads();

    // ---- Phase F: relabel prefix + perm + globals ----
    int remb[4], cnt4 = 0;
    for (int t = 0; t < 4; ++t) {
        remb[t] = ((centerm >> t) & 1) && !((selfm >> t) & 1);
        cnt4 += remb[t];
    }
    int inc2 = cnt4;
    for (int off = 1; off < 64; off <<= 1) {
        int v = __shfl_up(inc2, off);
        if (lane >= off) inc2 += v;
    }
    if (lane == 63) wt[wv] = inc2;
    __syncthreads();
    if (wv == 0 && lane < 16) {
        int v = wt[lane];
        for (int off = 1; off < 16; off <<= 1) {
            int u2 = __shfl_up(v, off);
            if (lane >= off) v += u2;
        }
        wt[lane] = v;
    }
    __syncthreads();
    int woff2 = (wv > 0) ? wt[wv - 1] : 0;
    int run = woff2 + inc2 - cnt4;
    for (int t = 0; t < 4; ++t) {
        int v = 4 * tid + t;
        relab_g[v] = run;
        if (remb[t]) { perm_a[run] = v; ++run; }
        rem_g[v] = remb[t];
    }
    if (tid == 1023) nkeep_g[0] = run;
}

// ---------------- K56: all outputs; x region is pure atomic-add over memset-0 --------
__global__ void k56_outputs(const float* __restrict__ x, const int* __restrict__ map_g,
                            const int* __restrict__ rem_g, const int* __restrict__ relab_g,
                            const int* __restrict__ perm_a, const int* __restrict__ ei,
                            const int* __restrict__ batch, const int* __restrict__ nkeep_g,
                            float* __restrict__ out) {
    int idx = blockIdx.x * blockDim.x + threadIdx.x;
    if (idx < NN * ND) {
        int n = idx >> 6, d = idx & 63;
        int m = map_g[n];                 // m==n for centers & kept free nodes
        if (rem_g[m]) atomicAdd(&out[relab_g[m] * ND + d], x[idx]);
    } else if (idx < NN * ND + 2 * NE) {
        int e = idx - NN * ND;
        int row = e >> 16;                // NE == 1<<16
        int ee = e & (NE - 1);
        int s = ei[ee], t = ei[NE + ee];
        bool valid = (rem_g[s] != 0) && (rem_g[t] != 0);
        int endp = (row == 0) ? s : t;
        out[idx] = valid ? (float)relab_g[endp] : -1.0f;
    } else if (idx < NN * ND + 2 * NE + NN) {
        int r = idx - (NN * ND + 2 * NE);
        int nk = nkeep_g[0];
        out[idx] = (r < nk) ? (float)batch[perm_a[r]] : -1.0f;
    } else if (idx < NN * ND + 2 * NE + 2 * NN) {
        int r = idx - (NN * ND + 2 * NE + NN);
        int nk = nkeep_g[0];
        out[idx] = (r < nk) ? (float)perm_a[r] : -1.0f;
    }
}

extern "C" void kernel_launch(void* const* d_in, const int* in_sizes, int n_in,
                              void* d_out, int out_size, void* d_ws, size_t ws_size,
                              hipStream_t stream) {
    const float* x     = (const float*)d_in[0];
    const int*   ei    = (const int*)d_in[1];
    const int*   batch = (const int*)d_in[2];
    const float* wrel  = (const float*)d_in[3];
    const float* wroot = (const float*)d_in[4];
    const float* b     = (const float*)d_in[5];

    char* ws = (char*)d_ws;
    double* srel  = (double*)(ws + 0);        // 32768
    double* sroot = (double*)(ws + 32768);    // 32768
    int*    map_g = (int*)(ws + 65536);       // 16384
    int*    rem_g = (int*)(ws + 81920);       // 16384
    int*    relab = (int*)(ws + 98304);       // 16384
    int*    perma = (int*)(ws + 114688);      // 16384
    int*    nkeep = (int*)(ws + 131072);      // 64

    float* out = (float*)d_out;

    hipMemsetAsync(out, 0, NN * ND * sizeof(float), stream);   // x_pooled base = 0
    k1_node_dots<<<NN * ND / 256, 256, 0, stream>>>(x, wrel, wroot, srel, sroot);
    k34_sort_contract<<<1, 1024, 0, stream>>>(srel, sroot, b, ei, map_g, rem_g, relab,
                                              perma, nkeep);
    int total_out = NN * ND + 2 * NE + 2 * NN;  // 401408
    k56_outputs<<<(total_out + 255) / 256, 256, 0, stream>>>(x, map_g, rem_g, relab,
                                                             perma, ei, batch, nkeep, out);
}

// Round 7
// 160.682 us; speedup vs baseline: 4.5760x; 1.2228x over previous
//
#include <hip/hip_runtime.h>

#define NN 4096
#define NE 65536
#define ND 64

// ---------------- K1: per-node dot products (srel, sroot only) ----------------
__global__ void k1_node_dots(const float* __restrict__ x, const float* __restrict__ wrel,
                             const float* __restrict__ wroot, double* __restrict__ srel,
                             double* __restrict__ sroot) {
    int gt = blockIdx.x * blockDim.x + threadIdx.x;
    int node = gt >> 6, lane = gt & 63;
    if (node >= NN) return;
    double xv = (double)x[node * ND + lane];
    double pr = xv * (double)wrel[lane];
    double po = xv * (double)wroot[lane];
    for (int off = 32; off > 0; off >>= 1) {
        pr += __shfl_down(pr, off);
        po += __shfl_down(po, off);
    }
    if (lane == 0) {
        srel[node] = pr;
        sroot[node] = po;
    }
}

// ---------------- K34: CSR + keys + SORT-FREE barrier-free fixpoint ----------------
// Order comparisons use the key directly: earlier(u,v) <=> key_u < key_v where
// key = (~mono_f32_score)<<12 | node  (same order & ties as stable argsort(-score)).
// skey[node] u64 = (~mono)<<14 | node<<2 | stat packs order+status: ONE ds_read_b64
// per entry visit. stat updates only touch the low 2 bits => torn reads harmless.
// LDS: incsr u16 [0,128K). aux 32K: cursor i32 [0,16K) (ph 1-4) -> srel f64 [0,32K)
// (ph 5-6) -> skey u64 [0,32K) (ph 7+). wt ints @ aux+20544 (ph 2 scan, ph F scan).
__global__ void __launch_bounds__(1024) k34_contract(
        const double* __restrict__ srel, const double* __restrict__ sroot,
        const float* __restrict__ bptr, const int* __restrict__ ei,
        int* __restrict__ map_g, int* __restrict__ rem_g, int* __restrict__ relab_g,
        int* __restrict__ perm_a, int* __restrict__ nkeep_g) {
    __shared__ __align__(16) char buf[163840];
    unsigned short* incsr = (unsigned short*)buf;
    char* aux = buf + 131072;
    int* cursor = (int*)aux;
    double* srel_lds = (double*)aux;
    volatile unsigned long long* skey = (volatile unsigned long long*)aux;
    int* wt = (int*)(aux + 20544);
    int tid = threadIdx.x, lane = tid & 63, wv = tid >> 6;

    // ---- Phase 1: in-degree count (LDS atomics) ----
    for (int n = tid; n < NN; n += 1024) cursor[n] = 0;
    __syncthreads();
    const int4* eid4 = (const int4*)(ei + NE);
    for (int i = tid; i < NE / 4; i += 1024) {
        int4 q = eid4[i];
        atomicAdd(&cursor[q.x], 1);
        atomicAdd(&cursor[q.y], 1);
        atomicAdd(&cursor[q.z], 1);
        atomicAdd(&cursor[q.w], 1);
    }
    __syncthreads();

    // ---- Phase 2: exclusive prefix (wave scan); row starts in regs ----
    int t0 = cursor[4 * tid], t1 = cursor[4 * tid + 1];
    int t2 = cursor[4 * tid + 2], t3 = cursor[4 * tid + 3];
    int tot = t0 + t1 + t2 + t3;
    int inc = tot;
    for (int off = 1; off < 64; off <<= 1) {
        int v = __shfl_up(inc, off);
        if (lane >= off) inc += v;
    }
    if (lane == 63) wt[wv] = inc;
    __syncthreads();
    if (wv == 0 && lane < 16) {
        int v = wt[lane];
        for (int off = 1; off < 16; off <<= 1) {
            int u2 = __shfl_up(v, off);
            if (lane >= off) v += u2;
        }
        wt[lane] = v;
    }
    __syncthreads();
    int waveoff = (wv > 0) ? wt[wv - 1] : 0;
    int excl = waveoff + inc - tot;
    int rs4[4], re4[4];
    rs4[0] = excl; rs4[1] = excl + t0; rs4[2] = excl + t0 + t1; rs4[3] = excl + t0 + t1 + t2;
    cursor[4 * tid]     = rs4[0];
    cursor[4 * tid + 1] = rs4[1];
    cursor[4 * tid + 2] = rs4[2];
    cursor[4 * tid + 3] = rs4[3];
    __syncthreads();

    // ---- Phase 3: scatter in-edges (row = dst, entry = src node id) ----
    const int4* eis4 = (const int4*)ei;
    for (int i = tid; i < NE / 4; i += 1024) {
        int4 s = eis4[i];
        int4 d = eid4[i];
        incsr[atomicAdd(&cursor[d.x], 1)] = (unsigned short)s.x;
        incsr[atomicAdd(&cursor[d.y], 1)] = (unsigned short)s.y;
        incsr[atomicAdd(&cursor[d.z], 1)] = (unsigned short)s.z;
        incsr[atomicAdd(&cursor[d.w], 1)] = (unsigned short)s.w;
    }
    __syncthreads();
    for (int t = 0; t < 4; ++t) re4[t] = cursor[4 * tid + t];   // row ends
    __syncthreads();   // cursor region now free

    // ---- Phase 5: stage srel into LDS (aliases cursor region) ----
    {
        double2* sl2 = (double2*)aux;
        const double2* sg2 = (const double2*)srel;
        for (int i = tid; i < NN / 2; i += 1024) sl2[i] = sg2[i];
    }
    __syncthreads();

    // ---- Phase 6: agg row-gather from LDS + key/base computation (regs only) ----
    double bv = (double)bptr[0];
    unsigned long long base4[4];
    for (int t = 0; t < 4; ++t) {
        int v = 4 * tid + t;
        double s = 0.0;
        for (int e = rs4[t]; e < re4[t]; ++e) s += srel_lds[(int)incsr[e]];
        double arg = s + sroot[v] + bv;
        float sc = tanhf((float)arg);                    // f32 saturation => ref ties
        unsigned m = __float_as_uint(sc);
        m = (m & 0x80000000u) ? ~m : (m | 0x80000000u);  // monotone ascending
        base4[t] = ((unsigned long long)(~m) << 14) | ((unsigned long long)v << 2);
    }
    __syncthreads();   // all srel_lds reads done before skey overwrites the region

    // ---- Phase 7: init skey table ----
    for (int t = 0; t < 4; ++t) skey[4 * tid + t] = base4[t];
    __syncthreads();

    // ---- Phase 8, round 0: filter rows (keep earlier in-nbrs only, note self) ----
    unsigned long long pk4[4], minC4[4];
    unsigned resolved = 0, centerm = 0, selfm = 0;
    for (int t = 0; t < 4; ++t) {
        int v = 4 * tid + t;
        unsigned long long pkv = base4[t] >> 2;
        pk4[t] = pkv;
        minC4[t] = ~0ULL;
        int w = rs4[t];
        for (int e = rs4[t]; e < re4[t]; ++e) {
            int u = (int)incsr[e];
            if (u == v) { selfm |= 1u << t; continue; }
            unsigned long long ku = skey[u] >> 2;        // stat bits shifted out
            if (ku < pkv) incsr[w++] = (unsigned short)u;
        }
        re4[t] = w;
        if (w == rs4[t]) {                               // no earlier in-nbrs: center
            map_g[v] = v;
            skey[v] = base4[t] | 1ULL;
            centerm |= 1u << t; resolved |= 1u << t;
        }
    }

    // ---- Phase 8b: barrier-free monotone dataflow fixpoint ----
    int guard = 0;
    while (resolved != 0xFu && guard < 1000000) {
        ++guard;
        bool prog = false;
        for (int t = 0; t < 4; ++t) {
            if (resolved & (1u << t)) continue;
            int v = 4 * tid + t;
            int lo = rs4[t], hi = re4[t];
            unsigned long long minU = ~0ULL, mC = minC4[t];
            int w = lo;
            for (int e = lo; e < hi; ++e) {
                int u = (int)incsr[e];
                unsigned long long sk = skey[u];
                int st = (int)(sk & 3ULL);
                unsigned long long ku = sk >> 2;
                if (st == 0) { incsr[w++] = (unsigned short)u; if (ku < minU) minU = ku; }
                else if (st == 1) { if (ku < mC) mC = ku; }
                // st==2: absorbed, drop
            }
            if (w != hi) prog = true;
            re4[t] = w; minC4[t] = mC;
            if (mC < minU) {                             // first absorber known
                map_g[v] = (int)((mC >> 2) & 0xFFFULL);  // decode node id
                skey[v] = (pk4[t] << 2) | 2ULL;
                resolved |= 1u << t; prog = true;
            } else if (w == lo) {                        // all earlier resolved non-center
                map_g[v] = v;
                skey[v] = (pk4[t] << 2) | 1ULL;
                centerm |= 1u << t; resolved |= 1u << t; prog = true;
            }
        }
        if (!prog) __builtin_amdgcn_s_sleep(1);
    }
    __syncthreads();

    // ---- Phase F: relabel prefix + perm + globals ----
    int remb[4], cnt4 = 0;
    for (int t = 0; t < 4; ++t) {
        remb[t] = ((centerm >> t) & 1) && !((selfm >> t) & 1);
        cnt4 += remb[t];
    }
    int inc2 = cnt4;
    for (int off = 1; off < 64; off <<= 1) {
        int v = __shfl_up(inc2, off);
        if (lane >= off) inc2 += v;
    }
    if (lane == 63) wt[wv] = inc2;
    __syncthreads();
    if (wv == 0 && lane < 16) {
        int v = wt[lane];
        for (int off = 1; off < 16; off <<= 1) {
            int u2 = __shfl_up(v, off);
            if (lane >= off) v += u2;
        }
        wt[lane] = v;
    }
    __syncthreads();
    int woff2 = (wv > 0) ? wt[wv - 1] : 0;
    int run = woff2 + inc2 - cnt4;
    for (int t = 0; t < 4; ++t) {
        int v = 4 * tid + t;
        relab_g[v] = run;
        if (remb[t]) { perm_a[run] = v; ++run; }
        rem_g[v] = remb[t];
    }
    if (tid == 1023) nkeep_g[0] = run;
}

// ---------------- K56: all outputs; x region is pure atomic-add over memset-0 --------
__global__ void k56_outputs(const float* __restrict__ x, const int* __restrict__ map_g,
                            const int* __restrict__ rem_g, const int* __restrict__ relab_g,
                            const int* __restrict__ perm_a, const int* __restrict__ ei,
                            const int* __restrict__ batch, const int* __restrict__ nkeep_g,
                            float* __restrict__ out) {
    int idx = blockIdx.x * blockDim.x + threadIdx.x;
    if (idx < NN * ND) {
        int n = idx >> 6, d = idx & 63;
        int m = map_g[n];                 // m==n for centers & kept free nodes
        if (rem_g[m]) atomicAdd(&out[relab_g[m] * ND + d], x[idx]);
    } else if (idx < NN * ND + 2 * NE) {
        int e = idx - NN * ND;
        int row = e >> 16;                // NE == 1<<16
        int ee = e & (NE - 1);
        int s = ei[ee], t = ei[NE + ee];
        bool valid = (rem_g[s] != 0) && (rem_g[t] != 0);
        int endp = (row == 0) ? s : t;
        out[idx] = valid ? (float)relab_g[endp] : -1.0f;
    } else if (idx < NN * ND + 2 * NE + NN) {
        int r = idx - (NN * ND + 2 * NE);
        int nk = nkeep_g[0];
        out[idx] = (r < nk) ? (float)batch[perm_a[r]] : -1.0f;
    } else if (idx < NN * ND + 2 * NE + 2 * NN) {
        int r = idx - (NN * ND + 2 * NE + NN);
        int nk = nkeep_g[0];
        out[idx] = (r < nk) ? (float)perm_a[r] : -1.0f;
    }
}

extern "C" void kernel_launch(void* const* d_in, const int* in_sizes, int n_in,
                              void* d_out, int out_size, void* d_ws, size_t ws_size,
                              hipStream_t stream) {
    const float* x     = (const float*)d_in[0];
    const int*   ei    = (const int*)d_in[1];
    const int*   batch = (const int*)d_in[2];
    const float* wrel  = (const float*)d_in[3];
    const float* wroot = (const float*)d_in[4];
    const float* b     = (const float*)d_in[5];

    char* ws = (char*)d_ws;
    double* srel  = (double*)(ws + 0);        // 32768
    double* sroot = (double*)(ws + 32768);    // 32768
    int*    map_g = (int*)(ws + 65536);       // 16384
    int*    rem_g = (int*)(ws + 81920);       // 16384
    int*    relab = (int*)(ws + 98304);       // 16384
    int*    perma = (int*)(ws + 114688);      // 16384
    int*    nkeep = (int*)(ws + 131072);      // 64

    float* out = (float*)d_out;

    hipMemsetAsync(out, 0, NN * ND * sizeof(float), stream);   // x_pooled base = 0
    k1_node_dots<<<NN * ND / 256, 256, 0, stream>>>(x, wrel, wroot, srel, sroot);
    k34_contract<<<1, 1024, 0, stream>>>(srel, sroot, b, ei, map_g, rem_g, relab,
                                         perma, nkeep);
    int total_out = NN * ND + 2 * NE + 2 * NN;  // 401408
    k56_outputs<<<(total_out + 255) / 256, 256, 0, stream>>>(x, map_g, rem_g, relab,
                                                             perma, ei, batch, nkeep, out);
}